// Round 6
// baseline (175.686 us; speedup 1.0000x reference)
//
#include <hip/hip_runtime.h>
#include <hip/hip_bf16.h>
#include <cstdint>
#include <cmath>

// Shapes (hard-coded): B=4, S=4096, D=1024, DK=DV=128.
// ws layout: Qb[16384][128]bf16 @0 (4MB) | Kb @4MB | Vt[B][128][4096]bf16 @8MB
//            | Wtq bf16[128][1024] @12MB | Wtk | Wtv (ends 12.75MB)
//            | Po[nsplit][16384][128]f32 @13MB | ml[nsplit][16384][2]f32 after.

typedef __bf16 bf16x8 __attribute__((ext_vector_type(8)));
typedef float f32x4 __attribute__((ext_vector_type(4)));
typedef float f32x16 __attribute__((ext_vector_type(16)));

__device__ __forceinline__ unsigned short f2bf(float f) {
  unsigned u = __float_as_uint(f);
  u += 0x7fffu + ((u >> 16) & 1u);   // RNE
  return (unsigned short)(u >> 16);
}

__device__ __forceinline__ bf16x8 ld_frag(const char* p) {
  uint4 u = *reinterpret_cast<const uint4*>(p);
  return __builtin_bit_cast(bf16x8, u);
}

__device__ __forceinline__ unsigned cvtpk_bf16(float lo, float hi) {
  unsigned r;
  asm("v_cvt_pk_bf16_f32 %0, %1, %2" : "=v"(r) : "v"(lo), "v"(hi));
  return r;
}

__device__ __forceinline__ void pl32swap(unsigned &a, unsigned &b) {
  asm("v_permlane32_swap_b32 %0, %1" : "+v"(a), "+v"(b));
}

__device__ __forceinline__ bf16x8 mk_frag(unsigned w0, unsigned w1, unsigned w2, unsigned w3) {
  uint4 u{w0, w1, w2, w3};
  return __builtin_bit_cast(bf16x8, u);
}

__device__ __forceinline__ bf16x8 cvt_frag(const float4& f0, const float4& f1) {
  return mk_frag(cvtpk_bf16(f0.x, f0.y), cvtpk_bf16(f0.z, f0.w),
                 cvtpk_bf16(f1.x, f1.y), cvtpk_bf16(f1.z, f1.w));
}

// Q is pre-scaled by (1/sqrt(128)) * log2(e) so softmax uses exp2 directly.
#define QSCALE_LOG2E 0.12751744f

// ---------------- W transpose: [1024][128] f32 -> [128][1024] bf16 ----------
__global__ __launch_bounds__(256) void prep_wt_kernel(
    const float* __restrict__ W0, const float* __restrict__ W1, const float* __restrict__ W2,
    unsigned short* __restrict__ T0, unsigned short* __restrict__ T1,
    unsigned short* __restrict__ T2) {
  const int mode = blockIdx.z;
  const float* W = (mode == 0) ? W0 : (mode == 1) ? W1 : W2;
  unsigned short* Wt = (mode == 0) ? T0 : (mode == 1) ? T1 : T2;
  __shared__ float tile[64][65];
  int kt = blockIdx.x, nt = blockIdx.y;   // (16, 2)
  int tid = threadIdx.x;
  int c = tid & 63;
  int r0 = (tid >> 6) * 16;
#pragma unroll
  for (int i = 0; i < 16; ++i) {
    int r = r0 + i;
    tile[r][c] = W[(size_t)(kt * 64 + r) * 128 + nt * 64 + c];
  }
  __syncthreads();
#pragma unroll
  for (int i = 0; i < 16; ++i) {
    int n = r0 + i;
    Wt[(size_t)(nt * 64 + n) * 1024 + kt * 64 + c] = f2bf(tile[c][n]);
  }
}

// ---------------- projections: X[16384][1024]f32 @ Wt -> bf16 outputs -------
// LDS-free, barrier-free: each wave owns 16 M-rows x full N=128.
// A fragments loaded global->reg (line-perfect for fp32), W frags from L2.
__global__ __launch_bounds__(256, 4) void proj_kernel(
    const float* __restrict__ qx, const float* __restrict__ kx, const float* __restrict__ vx,
    const unsigned short* __restrict__ Wtq, const unsigned short* __restrict__ Wtk,
    const unsigned short* __restrict__ Wtv,
    const float* __restrict__ bq, const float* __restrict__ bk, const float* __restrict__ bv,
    unsigned short* __restrict__ Qb, unsigned short* __restrict__ Kb,
    unsigned short* __restrict__ Vtb) {
  const int mode = blockIdx.y;  // 0=Q 1=K 2=V
  const float* x = (mode == 0) ? qx : (mode == 1) ? kx : vx;
  const unsigned short* Wt = (mode == 0) ? Wtq : (mode == 1) ? Wtk : Wtv;
  const float* bias = (mode == 0) ? bq : (mode == 1) ? bk : bv;

  const int tid = threadIdx.x;
  const int lane = tid & 63, wid = tid >> 6;
  const int l15 = lane & 15, hi = lane >> 4;
  const long m0 = (long)blockIdx.x * 64 + wid * 16;   // wave's 16 rows

  // A: lane (l15,hi) reads row m0+l15, k = t*64 + kk*32 + hi*8 (8 f32 = 2 float4)
  const float* abase = x + (m0 + l15) * 1024 + hi * 8;
  // W: frag (ni,kk): 16B at Wt[(ni*16+l15)][t*64 + kk*32 + hi*8] bf16
  const char* wbase = (const char*)Wt + (size_t)l15 * 2048 + hi * 16;

  f32x4 acc[8];
#pragma unroll
  for (int i = 0; i < 8; ++i) acc[i] = f32x4{0.f, 0.f, 0.f, 0.f};

  // prologue: A for t=0, W(ni=0) for t=0
  float4 a00 = *reinterpret_cast<const float4*>(abase + 0);
  float4 a01 = *reinterpret_cast<const float4*>(abase + 4);
  float4 a10 = *reinterpret_cast<const float4*>(abase + 32);
  float4 a11 = *reinterpret_cast<const float4*>(abase + 36);

#pragma unroll 1
  for (int t = 0; t < 16; ++t) {
    bf16x8 af0 = cvt_frag(a00, a01);
    bf16x8 af1 = cvt_frag(a10, a11);
    if (t < 15) {
      const float* an = abase + (t + 1) * 64;
      a00 = *reinterpret_cast<const float4*>(an + 0);
      a01 = *reinterpret_cast<const float4*>(an + 4);
      a10 = *reinterpret_cast<const float4*>(an + 32);
      a11 = *reinterpret_cast<const float4*>(an + 36);
    }
    const char* wt_ = wbase + t * 128;
#pragma unroll
    for (int ni = 0; ni < 8; ++ni) {
      bf16x8 wf0 = ld_frag(wt_ + (size_t)ni * 32768);
      bf16x8 wf1 = ld_frag(wt_ + (size_t)ni * 32768 + 64);
      acc[ni] = __builtin_amdgcn_mfma_f32_16x16x32_bf16(af0, wf0, acc[ni], 0, 0, 0);
      acc[ni] = __builtin_amdgcn_mfma_f32_16x16x32_bf16(af1, wf1, acc[ni], 0, 0, 0);
    }
  }

  // epilogue: +bias, (Q: * scale), store. C: col(n16)=l15, row(m)=hi*4+reg.
#pragma unroll
  for (int ni = 0; ni < 8; ++ni) {
    int n = ni * 16 + l15;
    float bv_ = bias[n];
    long m = m0 + hi * 4;
    f32x4 a = acc[ni];
    if (mode == 2) {
      int bb = (int)(m >> 12);
      int s = (int)(m & 4095);
      ushort4 pk;
      pk.x = f2bf(a.x + bv_); pk.y = f2bf(a.y + bv_);
      pk.z = f2bf(a.z + bv_); pk.w = f2bf(a.w + bv_);
      *reinterpret_cast<ushort4*>(Vtb + ((size_t)(bb * 128 + n)) * 4096 + s) = pk;
    } else {
      const float sc = (mode == 0) ? QSCALE_LOG2E : 1.0f;
      unsigned short* outp = (mode == 0) ? Qb : Kb;
      outp[(m + 0) * 128 + n] = f2bf((a.x + bv_) * sc);
      outp[(m + 1) * 128 + n] = f2bf((a.y + bv_) * sc);
      outp[(m + 2) * 128 + n] = f2bf((a.z + bv_) * sc);
      outp[(m + 3) * 128 + n] = f2bf((a.w + bv_) * sc);
    }
  }
}

// ---------------- flash attention (32x32 swapped-operand, KV-split) ---------
__global__ __launch_bounds__(256, 2) void attn_kernel(
    const unsigned short* __restrict__ Qb, const unsigned short* __restrict__ Kb,
    const unsigned short* __restrict__ Vtb, float* __restrict__ Po,
    float* __restrict__ ml, int tps) {
  __shared__ uint4 ldsK4[1024];  // 64 kv-rows x 128 d bf16, swizzled (16KB)
  __shared__ uint4 ldsV4[1024];  // 128 dv-rows x 64 k bf16, swizzled (16KB)
  char* ldsK = (char*)ldsK4;
  char* ldsV = (char*)ldsV4;

  const int tid = threadIdx.x;
  const int lane = tid & 63, wid = tid >> 6;
  const int l31 = lane & 31, hi = lane >> 5;
  const int split = blockIdx.y;
  const int b = blockIdx.z;
  const int qbase = blockIdx.x * 128 + wid * 32;  // within batch
  const size_t growq = (size_t)b * 4096 + qbase + l31;

  // Q fragments (B-operand): qf[kt] elem e <-> d = kt*16 + hi*8 + e
  bf16x8 qf[8];
  {
    const unsigned short* qp = Qb + growq * 128 + hi * 8;
#pragma unroll
    for (int kt = 0; kt < 8; ++kt)
      qf[kt] = __builtin_bit_cast(bf16x8, *reinterpret_cast<const uint4*>(qp + kt * 16));
  }

  f32x16 oacc[4];
#pragma unroll
  for (int d = 0; d < 4; ++d)
#pragma unroll
    for (int j = 0; j < 16; ++j) oacc[d][j] = 0.f;
  float mrun = -INFINITY, lrun = 0.f;

  const int t0 = split * tps, t1 = t0 + tps;

  for (int t = t0; t < t1; ++t) {
    const int kv0 = t * 64;
    const char* kg = (const char*)Kb + ((size_t)(b * 4096) + kv0) * 256;
#pragma unroll
    for (int i = 0; i < 4; ++i) {
      int u = tid + 256 * i;
      int row = u >> 4, c = u & 15;
      uint4 val = *reinterpret_cast<const uint4*>(kg + row * 256 + c * 16);
      *reinterpret_cast<uint4*>(ldsK + ((row * 256 + c * 16) ^ ((row & 7) << 4))) = val;
    }
    const char* vg = (const char*)Vtb + (size_t)b * 128 * 4096 * 2 + (size_t)kv0 * 2;
#pragma unroll
    for (int i = 0; i < 4; ++i) {
      int u = tid + 256 * i;
      int dv = u >> 3, c = u & 7;
      uint4 val = *reinterpret_cast<const uint4*>(vg + (size_t)dv * 8192 + c * 16);
      *reinterpret_cast<uint4*>(ldsV + ((dv * 128 + c * 16) ^ ((dv & 7) << 4))) = val;
    }
    __syncthreads();

    // ---- QK^T (swapped): sc_c[reg] = S[kv = (reg&3)+8*(reg>>2)+4*hi + 32c][q = l31]
    f32x16 sc0, sc1;
#pragma unroll
    for (int j = 0; j < 16; ++j) { sc0[j] = 0.f; sc1[j] = 0.f; }
    __builtin_amdgcn_s_setprio(1);
#pragma unroll
    for (int kvb = 0; kvb < 2; ++kvb) {
      int row = kvb * 32 + l31;
      int rowoff = row * 256, swz = (row & 7) << 4;
#pragma unroll
      for (int kt = 0; kt < 8; ++kt) {
        bf16x8 kf = ld_frag(ldsK + ((rowoff + kt * 32 + hi * 16) ^ swz));
        if (kvb == 0) sc0 = __builtin_amdgcn_mfma_f32_32x32x16_bf16(kf, qf[kt], sc0, 0, 0, 0);
        else          sc1 = __builtin_amdgcn_mfma_f32_32x32x16_bf16(kf, qf[kt], sc1, 0, 0, 0);
      }
    }
    __builtin_amdgcn_s_setprio(0);

    // ---- online softmax, fully per-lane (q = l31)
    float tmx[16];
#pragma unroll
    for (int i = 0; i < 16; ++i) tmx[i] = fmaxf(sc0[i], sc1[i]);
#pragma unroll
    for (int s = 8; s > 0; s >>= 1)
#pragma unroll
      for (int i = 0; i < s; ++i) tmx[i] = fmaxf(tmx[i], tmx[i + s]);
    float mt = tmx[0];
    mt = fmaxf(mt, __shfl_xor(mt, 32));

    // defer-max (T13)
    if (!__all(mt - mrun <= 8.0f)) {
      float mnew = fmaxf(mrun, mt);
      float scl = exp2f(mrun - mnew);
      mrun = mnew;
      lrun *= scl;
#pragma unroll
      for (int d = 0; d < 4; ++d)
#pragma unroll
        for (int j = 0; j < 16; ++j) oacc[d][j] *= scl;
    }

    // P = exp2(S - m) in-register
#pragma unroll
    for (int i = 0; i < 16; ++i) {
      sc0[i] = exp2f(sc0[i] - mrun);
      sc1[i] = exp2f(sc1[i] - mrun);
    }
    float ts[16];
#pragma unroll
    for (int i = 0; i < 16; ++i) ts[i] = sc0[i] + sc1[i];
#pragma unroll
    for (int s = 8; s > 0; s >>= 1)
#pragma unroll
      for (int i = 0; i < s; ++i) ts[i] += ts[i + s];
    float psum = ts[0];
    psum += __shfl_xor(psum, 32);
    lrun += psum;

    // ---- P -> bf16 fragments via cvt_pk + permlane32_swap (T12)
    bf16x8 pa[4];
#pragma unroll
    for (int c = 0; c < 2; ++c) {
      const f32x16& p = c ? sc1 : sc0;
#pragma unroll
      for (int g = 0; g < 2; ++g) {
        const int base = g * 8;
        unsigned a0 = cvtpk_bf16(p[base + 0], p[base + 1]);
        unsigned b0 = cvtpk_bf16(p[base + 4], p[base + 5]);
        pl32swap(a0, b0);
        unsigned a1 = cvtpk_bf16(p[base + 2], p[base + 3]);
        unsigned b1 = cvtpk_bf16(p[base + 6], p[base + 7]);
        pl32swap(a1, b1);
        pa[c * 2 + g] = mk_frag(a0, a1, b0, b1);
      }
    }

    // ---- PV (swapped): oacc[dvb] += mfma(A=Vt rows, B=P^T)
    __builtin_amdgcn_s_setprio(1);
#pragma unroll
    for (int dvb = 0; dvb < 4; ++dvb) {
      int vrow = dvb * 32 + l31;
      int voff = vrow * 128, vswz = (vrow & 7) << 4;
#pragma unroll
      for (int tt = 0; tt < 4; ++tt) {
        bf16x8 vf = ld_frag(ldsV + ((voff + tt * 32 + hi * 16) ^ vswz));
        oacc[dvb] = __builtin_amdgcn_mfma_f32_32x32x16_bf16(vf, pa[tt], oacc[dvb], 0, 0, 0);
      }
    }
    __builtin_amdgcn_s_setprio(0);
    __syncthreads();
  }

  // ---- epilogue: ml + O^T -> O via per-wave LDS transpose, coalesced stores
  if (hi == 0) {
    float* mlp = ml + (size_t)split * 32768 + growq * 2;
    mlp[0] = mrun; mlp[1] = lrun;
  }

  float* po = Po + ((size_t)split << 21) + ((size_t)b * 4096 + qbase) * 128;
  char* tbase = ldsK + wid * 4096;  // 32q x 32dv f32 = 4KB per wave
  for (int dvb = 0; dvb < 4; ++dvb) {
#pragma unroll
    for (int g = 0; g < 4; ++g) {
      float4 w4{oacc[dvb][g * 4 + 0], oacc[dvb][g * 4 + 1],
                oacc[dvb][g * 4 + 2], oacc[dvb][g * 4 + 3]};
      int off = (l31 * 128 + g * 32 + hi * 16) ^ ((l31 & 7) << 4);
      *reinterpret_cast<float4*>(tbase + off) = w4;
    }
    asm volatile("s_waitcnt lgkmcnt(0)" ::: "memory");
    __builtin_amdgcn_sched_barrier(0);
#pragma unroll
    for (int qq = 0; qq < 4; ++qq) {
      int q = qq * 8 + (lane >> 3);
      int off = (q * 128 + (lane & 7) * 16) ^ ((q & 7) << 4);
      float4 r4 = *reinterpret_cast<const float4*>(tbase + off);
      *reinterpret_cast<float4*>(po + (size_t)q * 128 + dvb * 32 + (lane & 7) * 4) = r4;
    }
    asm volatile("s_waitcnt lgkmcnt(0)" ::: "memory");
    __builtin_amdgcn_sched_barrier(0);
  }
}

// ---------------- combine partials ------------------------------------------
template <int NS>
__global__ __launch_bounds__(256) void combine_kernel(const float* __restrict__ Po,
                                                      const float* __restrict__ ml,
                                                      float* __restrict__ out) {
  int idx = blockIdx.x * 256 + threadIdx.x;  // 16384*32 float4-units
  int grow = idx >> 5;
  int c4 = (idx & 31) * 4;
  float m[NS], l[NS];
  float M = -INFINITY;
#pragma unroll
  for (int s = 0; s < NS; ++s) {
    m[s] = ml[(size_t)s * 32768 + grow * 2 + 0];
    l[s] = ml[(size_t)s * 32768 + grow * 2 + 1];
    M = fmaxf(M, m[s]);
  }
  float L = 0.f, w[NS];
#pragma unroll
  for (int s = 0; s < NS; ++s) {
    w[s] = exp2f(m[s] - M);   // log2 domain
    L += l[s] * w[s];
  }
  float invL = 1.0f / L;
  float4 acc = {0.f, 0.f, 0.f, 0.f};
#pragma unroll
  for (int s = 0; s < NS; ++s) {
    float4 p = *reinterpret_cast<const float4*>(Po + ((size_t)s << 21) + (size_t)grow * 128 + c4);
    acc.x += p.x * w[s]; acc.y += p.y * w[s];
    acc.z += p.z * w[s]; acc.w += p.w * w[s];
  }
  acc.x *= invL; acc.y *= invL; acc.z *= invL; acc.w *= invL;
  *reinterpret_cast<float4*>(out + (size_t)grow * 128 + c4) = acc;
}

extern "C" void kernel_launch(void* const* d_in, const int* in_sizes, int n_in,
                              void* d_out, int out_size, void* d_ws, size_t ws_size,
                              hipStream_t stream) {
  const float* q  = (const float*)d_in[0];
  const float* k  = (const float*)d_in[1];
  const float* v  = (const float*)d_in[2];
  const float* Wq = (const float*)d_in[3];
  const float* bq = (const float*)d_in[4];
  const float* Wk = (const float*)d_in[5];
  const float* bk = (const float*)d_in[6];
  const float* Wv = (const float*)d_in[7];
  const float* bv = (const float*)d_in[8];
  float* out = (float*)d_out;

  char* ws = (char*)d_ws;
  unsigned short* Qb  = (unsigned short*)(ws);
  unsigned short* Kb  = (unsigned short*)(ws + (4u << 20));
  unsigned short* Vtb = (unsigned short*)(ws + (8u << 20));
  unsigned short* Wtq = (unsigned short*)(ws + (12u << 20));
  unsigned short* Wtk = (unsigned short*)(ws + (12u << 20) + (256u << 10));
  unsigned short* Wtv = (unsigned short*)(ws + (12u << 20) + (512u << 10));

  const size_t base = (size_t)13 << 20;
  const size_t per = ((size_t)8 << 20) + ((size_t)128 << 10);
  int nsplit = 1;
  if (ws_size >= base + 4 * per) nsplit = 4;
  else if (ws_size >= base + 2 * per) nsplit = 2;
  float* Po = (float*)(ws + base);
  float* ml = (float*)(ws + base + (size_t)nsplit * ((size_t)8 << 20));

  prep_wt_kernel<<<dim3(16, 2, 3), 256, 0, stream>>>(Wq, Wk, Wv, Wtq, Wtk, Wtv);
  proj_kernel<<<dim3(256, 3), 256, 0, stream>>>(q, k, v, Wtq, Wtk, Wtv, bq, bk, bv, Qb, Kb, Vtb);
  attn_kernel<<<dim3(32, nsplit, 4), 256, 0, stream>>>(Qb, Kb, Vtb, Po, ml, 64 / nsplit);
  if (nsplit == 4)      combine_kernel<4><<<2048, 256, 0, stream>>>(Po, ml, out);
  else if (nsplit == 2) combine_kernel<2><<<2048, 256, 0, stream>>>(Po, ml, out);
  else                  combine_kernel<1><<<2048, 256, 0, stream>>>(Po, ml, out);
}

// Round 7
// 108.060 us; speedup vs baseline: 1.6258x; 1.6258x over previous
//
#include <hip/hip_runtime.h>
#include <hip/hip_bf16.h>
#include <cstdint>
#include <cmath>

// Shapes (hard-coded): B=4, S=4096, D=1024, DK=DV=128.
// ws layout: Qb[16384][128]bf16 @0 (4MB) | Kb @4MB | Vt[B][128][4096]bf16 @8MB
//            | Wtq bf16[128][1024] @12MB | Wtk | Wtv (ends 12.75MB)
//            | Po[nsplit][16384][128]f32 @13MB | ml[nsplit][16384][2]f32 after.

typedef __bf16 bf16x8 __attribute__((ext_vector_type(8)));
typedef float f32x4 __attribute__((ext_vector_type(4)));
typedef float f32x16 __attribute__((ext_vector_type(16)));

typedef const __attribute__((address_space(1))) unsigned int* gp_t;
typedef __attribute__((address_space(3))) unsigned int* lp_t;

__device__ __forceinline__ unsigned short f2bf(float f) {
  unsigned u = __float_as_uint(f);
  u += 0x7fffu + ((u >> 16) & 1u);   // RNE
  return (unsigned short)(u >> 16);
}

__device__ __forceinline__ bf16x8 ld_frag(const char* p) {
  uint4 u = *reinterpret_cast<const uint4*>(p);
  return __builtin_bit_cast(bf16x8, u);
}

__device__ __forceinline__ unsigned cvtpk_bf16(float lo, float hi) {
  unsigned r;
  asm("v_cvt_pk_bf16_f32 %0, %1, %2" : "=v"(r) : "v"(lo), "v"(hi));
  return r;
}

__device__ __forceinline__ void pl32swap(unsigned &a, unsigned &b) {
  asm("v_permlane32_swap_b32 %0, %1" : "+v"(a), "+v"(b));
}

__device__ __forceinline__ bf16x8 mk_frag(unsigned w0, unsigned w1, unsigned w2, unsigned w3) {
  uint4 u{w0, w1, w2, w3};
  return __builtin_bit_cast(bf16x8, u);
}

__device__ __forceinline__ bf16x8 cvt_frag(const float4& f0, const float4& f1) {
  return mk_frag(cvtpk_bf16(f0.x, f0.y), cvtpk_bf16(f0.z, f0.w),
                 cvtpk_bf16(f1.x, f1.y), cvtpk_bf16(f1.z, f1.w));
}

// Q is pre-scaled by (1/sqrt(128)) * log2(e) so softmax uses exp2 directly.
#define QSCALE_LOG2E 0.12751744f

// ---------------- W transpose: [1024][128] f32 -> [128][1024] bf16 ----------
__global__ __launch_bounds__(256) void prep_wt_kernel(
    const float* __restrict__ W0, const float* __restrict__ W1, const float* __restrict__ W2,
    unsigned short* __restrict__ T0, unsigned short* __restrict__ T1,
    unsigned short* __restrict__ T2) {
  const int mode = blockIdx.z;
  const float* W = (mode == 0) ? W0 : (mode == 1) ? W1 : W2;
  unsigned short* Wt = (mode == 0) ? T0 : (mode == 1) ? T1 : T2;
  __shared__ float tile[64][65];
  int kt = blockIdx.x, nt = blockIdx.y;   // (16, 2)
  int tid = threadIdx.x;
  int c = tid & 63;
  int r0 = (tid >> 6) * 16;
#pragma unroll
  for (int i = 0; i < 16; ++i) {
    int r = r0 + i;
    tile[r][c] = W[(size_t)(kt * 64 + r) * 128 + nt * 64 + c];
  }
  __syncthreads();
#pragma unroll
  for (int i = 0; i < 16; ++i) {
    int n = r0 + i;
    Wt[(size_t)(nt * 64 + n) * 1024 + kt * 64 + c] = f2bf(tile[c][n]);
  }
}

// ---------------- projections: X[16384][1024]f32 @ Wt -> bf16 outputs -------
// 64x128 tile, BK=64. A (fp32) and W (bf16) both staged via global_load_lds
// w16: linear LDS dest + inverse-swizzled global source (m201 pattern).
// Counted-vmcnt pipeline: wait vmcnt(8); barrier; compute; barrier; stage(t+2).
__global__ __launch_bounds__(256, 2) void proj_kernel(
    const float* __restrict__ qx, const float* __restrict__ kx, const float* __restrict__ vx,
    const unsigned short* __restrict__ Wtq, const unsigned short* __restrict__ Wtk,
    const unsigned short* __restrict__ Wtv,
    const float* __restrict__ bq, const float* __restrict__ bk, const float* __restrict__ bv,
    unsigned short* __restrict__ Qb, unsigned short* __restrict__ Kb,
    unsigned short* __restrict__ Vtb) {
  const int mode = blockIdx.y;  // 0=Q 1=K 2=V
  const float* x = (mode == 0) ? qx : (mode == 1) ? kx : vx;
  const unsigned short* Wt = (mode == 0) ? Wtq : (mode == 1) ? Wtk : Wtv;
  const float* bias = (mode == 0) ? bq : (mode == 1) ? bk : bv;

  __shared__ __align__(16) char lds[65536];  // A: 2x16KB @0, W: 2x16KB @32768

  const int tid = threadIdx.x;
  const int lane = tid & 63, wid = tid >> 6;
  const int l15 = lane & 15, hi = lane >> 4;
  const int wm = wid >> 1, wn = wid & 1;
  const long row0 = (long)blockIdx.x * 64;

  // A staging (fp32 [64 rows][64 k], 256B/row, 16KB/buf):
  //  linear LDS byte = i*4096 + tid*16 -> row = i*16 + (tid>>4),
  //  col32 = (tid>>1)&7, half16 = tid&1. Source col pre-swizzled: c' = c ^ (row&7).
  const int a_row = tid >> 4;                                 // + i*16
  const int a_c32s = ((tid >> 1) & 7) ^ ((tid >> 4) & 7);
  const char* a_src = (const char*)(x + (row0 + a_row) * 1024) + a_c32s * 32 + (tid & 1) * 16;

  // W staging (bf16 [128 rows][64 k], 128B/row, 16KB/buf):
  //  linear byte = i*4096 + tid*16 -> row = i*32 + (tid>>3), col16 = tid&7.
  const int w_c16s = (tid & 7) ^ ((tid >> 3) & 7);
  const char* w_src = (const char*)Wt + (size_t)(tid >> 3) * 2048 + w_c16s * 16;

  f32x4 acc[2][4];
#pragma unroll
  for (int i = 0; i < 2; ++i)
#pragma unroll
    for (int j = 0; j < 4; ++j) acc[i][j] = f32x4{0.f, 0.f, 0.f, 0.f};

#define PROJ_STAGE(ts, buf)                                                          \
  {                                                                                  \
    char* la_ = lds + (buf) * 16384;                                                 \
    char* lw_ = lds + 32768 + (buf) * 16384;                                         \
    _Pragma("unroll")                                                                \
    for (int i = 0; i < 4; ++i)                                                      \
      __builtin_amdgcn_global_load_lds((gp_t)(a_src + (size_t)i * 65536 + (ts) * 256),\
                                       (lp_t)(la_ + i * 4096 + wid * 1024), 16, 0, 0);\
    _Pragma("unroll")                                                                \
    for (int i = 0; i < 4; ++i)                                                      \
      __builtin_amdgcn_global_load_lds((gp_t)(w_src + (size_t)i * 65536 + (ts) * 128),\
                                       (lp_t)(lw_ + i * 4096 + wid * 1024), 16, 0, 0);\
  }

#define PROJ_COMPUTE(buf)                                                            \
  {                                                                                  \
    char* la_ = lds + (buf) * 16384;                                                 \
    char* lw_ = lds + 32768 + (buf) * 16384;                                         \
    _Pragma("unroll")                                                                \
    for (int kk = 0; kk < 2; ++kk) {                                                 \
      bf16x8 af[2], wf[4];                                                           \
      _Pragma("unroll")                                                              \
      for (int mi = 0; mi < 2; ++mi) {                                               \
        int row = wm * 32 + mi * 16 + l15;                                           \
        int base = (row * 256 + kk * 128 + hi * 32) ^ ((row & 7) << 5);              \
        float4 f0 = *reinterpret_cast<const float4*>(la_ + base);                    \
        float4 f1 = *reinterpret_cast<const float4*>(la_ + base + 16);               \
        af[mi] = cvt_frag(f0, f1);                                                   \
      }                                                                              \
      _Pragma("unroll")                                                              \
      for (int ni = 0; ni < 4; ++ni) {                                               \
        int row = wn * 64 + ni * 16 + l15;                                           \
        wf[ni] = ld_frag(lw_ + ((row * 128 + kk * 64 + hi * 16) ^ ((row & 7) << 4)));\
      }                                                                              \
      _Pragma("unroll")                                                              \
      for (int mi = 0; mi < 2; ++mi)                                                 \
        _Pragma("unroll")                                                            \
        for (int ni = 0; ni < 4; ++ni)                                               \
          acc[mi][ni] =                                                              \
              __builtin_amdgcn_mfma_f32_16x16x32_bf16(af[mi], wf[ni], acc[mi][ni], 0, 0, 0);\
    }                                                                                \
  }

  // prologue: two tiles in flight
  PROJ_STAGE(0, 0);
  PROJ_STAGE(1, 1);

#pragma unroll 1
  for (int t = 0; t < 15; ++t) {
    asm volatile("s_waitcnt vmcnt(8)" ::: "memory");  // tile t ready; t+1 in flight
    __builtin_amdgcn_s_barrier();
    PROJ_COMPUTE(t & 1);
    __builtin_amdgcn_s_barrier();                     // all waves done reading buf
    if (t + 2 < 16) PROJ_STAGE(t + 2, t & 1);
  }
  asm volatile("s_waitcnt vmcnt(0)" ::: "memory");    // last tile (t=15, buf 1)
  __builtin_amdgcn_s_barrier();
  PROJ_COMPUTE(1);

#undef PROJ_STAGE
#undef PROJ_COMPUTE

  // epilogue: +bias, (Q: * scale), store
#pragma unroll
  for (int ni = 0; ni < 4; ++ni) {
    int n = wn * 64 + ni * 16 + l15;
    float bv_ = bias[n];
#pragma unroll
    for (int mi = 0; mi < 2; ++mi) {
      long m = row0 + wm * 32 + mi * 16 + hi * 4;
      f32x4 a = acc[mi][ni];
      if (mode == 2) {
        int bb = (int)(m >> 12);
        int s = (int)(m & 4095);
        ushort4 pk;
        pk.x = f2bf(a.x + bv_); pk.y = f2bf(a.y + bv_);
        pk.z = f2bf(a.z + bv_); pk.w = f2bf(a.w + bv_);
        *reinterpret_cast<ushort4*>(Vtb + ((size_t)(bb * 128 + n)) * 4096 + s) = pk;
      } else {
        const float sc = (mode == 0) ? QSCALE_LOG2E : 1.0f;
        unsigned short* outp = (mode == 0) ? Qb : Kb;
        outp[(m + 0) * 128 + n] = f2bf((a.x + bv_) * sc);
        outp[(m + 1) * 128 + n] = f2bf((a.y + bv_) * sc);
        outp[(m + 2) * 128 + n] = f2bf((a.z + bv_) * sc);
        outp[(m + 3) * 128 + n] = f2bf((a.w + bv_) * sc);
      }
    }
  }
}

// ---------------- flash attention (32x32 swapped-operand, KV-split) ---------
__global__ __launch_bounds__(256, 2) void attn_kernel(
    const unsigned short* __restrict__ Qb, const unsigned short* __restrict__ Kb,
    const unsigned short* __restrict__ Vtb, float* __restrict__ Po,
    float* __restrict__ ml, int tps) {
  __shared__ uint4 ldsK4[1024];  // 64 kv-rows x 128 d bf16, swizzled (16KB)
  __shared__ uint4 ldsV4[1024];  // 128 dv-rows x 64 k bf16, swizzled (16KB)
  char* ldsK = (char*)ldsK4;
  char* ldsV = (char*)ldsV4;

  const int tid = threadIdx.x;
  const int lane = tid & 63, wid = tid >> 6;
  const int l31 = lane & 31, hi = lane >> 5;
  const int split = blockIdx.y;
  const int b = blockIdx.z;
  const int qbase = blockIdx.x * 128 + wid * 32;  // within batch
  const size_t growq = (size_t)b * 4096 + qbase + l31;

  // Q fragments (B-operand): qf[kt] elem e <-> d = kt*16 + hi*8 + e
  bf16x8 qf[8];
  {
    const unsigned short* qp = Qb + growq * 128 + hi * 8;
#pragma unroll
    for (int kt = 0; kt < 8; ++kt)
      qf[kt] = __builtin_bit_cast(bf16x8, *reinterpret_cast<const uint4*>(qp + kt * 16));
  }

  f32x16 oacc[4];
#pragma unroll
  for (int d = 0; d < 4; ++d)
#pragma unroll
    for (int j = 0; j < 16; ++j) oacc[d][j] = 0.f;
  float mrun = -INFINITY, lrun = 0.f;

  const int t0 = split * tps, t1 = t0 + tps;

  for (int t = t0; t < t1; ++t) {
    const int kv0 = t * 64;
    const char* kg = (const char*)Kb + ((size_t)(b * 4096) + kv0) * 256;
#pragma unroll
    for (int i = 0; i < 4; ++i) {
      int u = tid + 256 * i;
      int row = u >> 4, c = u & 15;
      uint4 val = *reinterpret_cast<const uint4*>(kg + row * 256 + c * 16);
      *reinterpret_cast<uint4*>(ldsK + ((row * 256 + c * 16) ^ ((row & 7) << 4))) = val;
    }
    const char* vg = (const char*)Vtb + (size_t)b * 128 * 4096 * 2 + (size_t)kv0 * 2;
#pragma unroll
    for (int i = 0; i < 4; ++i) {
      int u = tid + 256 * i;
      int dv = u >> 3, c = u & 7;
      uint4 val = *reinterpret_cast<const uint4*>(vg + (size_t)dv * 8192 + c * 16);
      *reinterpret_cast<uint4*>(ldsV + ((dv * 128 + c * 16) ^ ((dv & 7) << 4))) = val;
    }
    __syncthreads();

    // ---- QK^T (swapped): sc_c[reg] = S[kv = (reg&3)+8*(reg>>2)+4*hi + 32c][q = l31]
    f32x16 sc0, sc1;
#pragma unroll
    for (int j = 0; j < 16; ++j) { sc0[j] = 0.f; sc1[j] = 0.f; }
    __builtin_amdgcn_s_setprio(1);
#pragma unroll
    for (int kvb = 0; kvb < 2; ++kvb) {
      int row = kvb * 32 + l31;
      int rowoff = row * 256, swz = (row & 7) << 4;
#pragma unroll
      for (int kt = 0; kt < 8; ++kt) {
        bf16x8 kf = ld_frag(ldsK + ((rowoff + kt * 32 + hi * 16) ^ swz));
        if (kvb == 0) sc0 = __builtin_amdgcn_mfma_f32_32x32x16_bf16(kf, qf[kt], sc0, 0, 0, 0);
        else          sc1 = __builtin_amdgcn_mfma_f32_32x32x16_bf16(kf, qf[kt], sc1, 0, 0, 0);
      }
    }
    __builtin_amdgcn_s_setprio(0);

    // ---- online softmax, fully per-lane (q = l31)
    float tmx[16];
#pragma unroll
    for (int i = 0; i < 16; ++i) tmx[i] = fmaxf(sc0[i], sc1[i]);
#pragma unroll
    for (int s = 8; s > 0; s >>= 1)
#pragma unroll
      for (int i = 0; i < s; ++i) tmx[i] = fmaxf(tmx[i], tmx[i + s]);
    float mt = tmx[0];
    mt = fmaxf(mt, __shfl_xor(mt, 32));

    // defer-max (T13)
    if (!__all(mt - mrun <= 8.0f)) {
      float mnew = fmaxf(mrun, mt);
      float scl = exp2f(mrun - mnew);
      mrun = mnew;
      lrun *= scl;
#pragma unroll
      for (int d = 0; d < 4; ++d)
#pragma unroll
        for (int j = 0; j < 16; ++j) oacc[d][j] *= scl;
    }

    // P = exp2(S - m) in-register
#pragma unroll
    for (int i = 0; i < 16; ++i) {
      sc0[i] = exp2f(sc0[i] - mrun);
      sc1[i] = exp2f(sc1[i] - mrun);
    }
    float ts[16];
#pragma unroll
    for (int i = 0; i < 16; ++i) ts[i] = sc0[i] + sc1[i];
#pragma unroll
    for (int s = 8; s > 0; s >>= 1)
#pragma unroll
      for (int i = 0; i < s; ++i) ts[i] += ts[i + s];
    float psum = ts[0];
    psum += __shfl_xor(psum, 32);
    lrun += psum;

    // ---- P -> bf16 fragments via cvt_pk + permlane32_swap (T12)
    bf16x8 pa[4];
#pragma unroll
    for (int c = 0; c < 2; ++c) {
      const f32x16& p = c ? sc1 : sc0;
#pragma unroll
      for (int g = 0; g < 2; ++g) {
        const int base = g * 8;
        unsigned a0 = cvtpk_bf16(p[base + 0], p[base + 1]);
        unsigned b0 = cvtpk_bf16(p[base + 4], p[base + 5]);
        pl32swap(a0, b0);
        unsigned a1 = cvtpk_bf16(p[base + 2], p[base + 3]);
        unsigned b1 = cvtpk_bf16(p[base + 6], p[base + 7]);
        pl32swap(a1, b1);
        pa[c * 2 + g] = mk_frag(a0, a1, b0, b1);
      }
    }

    // ---- PV (swapped): oacc[dvb] += mfma(A=Vt rows, B=P^T)
    __builtin_amdgcn_s_setprio(1);
#pragma unroll
    for (int dvb = 0; dvb < 4; ++dvb) {
      int vrow = dvb * 32 + l31;
      int voff = vrow * 128, vswz = (vrow & 7) << 4;
#pragma unroll
      for (int tt = 0; tt < 4; ++tt) {
        bf16x8 vf = ld_frag(ldsV + ((voff + tt * 32 + hi * 16) ^ vswz));
        oacc[dvb] = __builtin_amdgcn_mfma_f32_32x32x16_bf16(vf, pa[tt], oacc[dvb], 0, 0, 0);
      }
    }
    __builtin_amdgcn_s_setprio(0);
    __syncthreads();
  }

  // ---- epilogue: ml + O^T -> O via per-wave LDS transpose, coalesced stores
  if (hi == 0) {
    float* mlp = ml + (size_t)split * 32768 + growq * 2;
    mlp[0] = mrun; mlp[1] = lrun;
  }

  float* po = Po + ((size_t)split << 21) + ((size_t)b * 4096 + qbase) * 128;
  char* tbase = ldsK + wid * 4096;  // 32q x 32dv f32 = 4KB per wave
  for (int dvb = 0; dvb < 4; ++dvb) {
#pragma unroll
    for (int g = 0; g < 4; ++g) {
      float4 w4{oacc[dvb][g * 4 + 0], oacc[dvb][g * 4 + 1],
                oacc[dvb][g * 4 + 2], oacc[dvb][g * 4 + 3]};
      int off = (l31 * 128 + g * 32 + hi * 16) ^ ((l31 & 7) << 4);
      *reinterpret_cast<float4*>(tbase + off) = w4;
    }
    asm volatile("s_waitcnt lgkmcnt(0)" ::: "memory");
    __builtin_amdgcn_sched_barrier(0);
#pragma unroll
    for (int qq = 0; qq < 4; ++qq) {
      int q = qq * 8 + (lane >> 3);
      int off = (q * 128 + (lane & 7) * 16) ^ ((q & 7) << 4);
      float4 r4 = *reinterpret_cast<const float4*>(tbase + off);
      *reinterpret_cast<float4*>(po + (size_t)q * 128 + dvb * 32 + (lane & 7) * 4) = r4;
    }
    asm volatile("s_waitcnt lgkmcnt(0)" ::: "memory");
    __builtin_amdgcn_sched_barrier(0);
  }
}

// ---------------- combine partials ------------------------------------------
template <int NS>
__global__ __launch_bounds__(256) void combine_kernel(const float* __restrict__ Po,
                                                      const float* __restrict__ ml,
                                                      float* __restrict__ out) {
  int idx = blockIdx.x * 256 + threadIdx.x;  // 16384*32 float4-units
  int grow = idx >> 5;
  int c4 = (idx & 31) * 4;
  float m[NS], l[NS];
  float M = -INFINITY;
#pragma unroll
  for (int s = 0; s < NS; ++s) {
    m[s] = ml[(size_t)s * 32768 + grow * 2 + 0];
    l[s] = ml[(size_t)s * 32768 + grow * 2 + 1];
    M = fmaxf(M, m[s]);
  }
  float L = 0.f, w[NS];
#pragma unroll
  for (int s = 0; s < NS; ++s) {
    w[s] = exp2f(m[s] - M);   // log2 domain
    L += l[s] * w[s];
  }
  float invL = 1.0f / L;
  float4 acc = {0.f, 0.f, 0.f, 0.f};
#pragma unroll
  for (int s = 0; s < NS; ++s) {
    float4 p = *reinterpret_cast<const float4*>(Po + ((size_t)s << 21) + (size_t)grow * 128 + c4);
    acc.x += p.x * w[s]; acc.y += p.y * w[s];
    acc.z += p.z * w[s]; acc.w += p.w * w[s];
  }
  acc.x *= invL; acc.y *= invL; acc.z *= invL; acc.w *= invL;
  *reinterpret_cast<float4*>(out + (size_t)grow * 128 + c4) = acc;
}

extern "C" void kernel_launch(void* const* d_in, const int* in_sizes, int n_in,
                              void* d_out, int out_size, void* d_ws, size_t ws_size,
                              hipStream_t stream) {
  const float* q  = (const float*)d_in[0];
  const float* k  = (const float*)d_in[1];
  const float* v  = (const float*)d_in[2];
  const float* Wq = (const float*)d_in[3];
  const float* bq = (const float*)d_in[4];
  const float* Wk = (const float*)d_in[5];
  const float* bk = (const float*)d_in[6];
  const float* Wv = (const float*)d_in[7];
  const float* bv = (const float*)d_in[8];
  float* out = (float*)d_out;

  char* ws = (char*)d_ws;
  unsigned short* Qb  = (unsigned short*)(ws);
  unsigned short* Kb  = (unsigned short*)(ws + (4u << 20));
  unsigned short* Vtb = (unsigned short*)(ws + (8u << 20));
  unsigned short* Wtq = (unsigned short*)(ws + (12u << 20));
  unsigned short* Wtk = (unsigned short*)(ws + (12u << 20) + (256u << 10));
  unsigned short* Wtv = (unsigned short*)(ws + (12u << 20) + (512u << 10));

  const size_t base = (size_t)13 << 20;
  const size_t per = ((size_t)8 << 20) + ((size_t)128 << 10);
  int nsplit = 1;
  if (ws_size >= base + 4 * per) nsplit = 4;
  else if (ws_size >= base + 2 * per) nsplit = 2;
  float* Po = (float*)(ws + base);
  float* ml = (float*)(ws + base + (size_t)nsplit * ((size_t)8 << 20));

  prep_wt_kernel<<<dim3(16, 2, 3), 256, 0, stream>>>(Wq, Wk, Wv, Wtq, Wtk, Wtv);
  proj_kernel<<<dim3(256, 3), 256, 0, stream>>>(q, k, v, Wtq, Wtk, Wtv, bq, bk, bv, Qb, Kb, Vtb);
  attn_kernel<<<dim3(32, nsplit, 4), 256, 0, stream>>>(Qb, Kb, Vtb, Po, ml, 64 / nsplit);
  if (nsplit == 4)      combine_kernel<4><<<2048, 256, 0, stream>>>(Po, ml, out);
  else if (nsplit == 2) combine_kernel<2><<<2048, 256, 0, stream>>>(Po, ml, out);
  else                  combine_kernel<1><<<2048, 256, 0, stream>>>(Po, ml, out);
}

// Round 8
// 105.189 us; speedup vs baseline: 1.6702x; 1.0273x over previous
//
#include <hip/hip_runtime.h>
#include <hip/hip_bf16.h>
#include <cstdint>
#include <cmath>

// Shapes (hard-coded): B=4, S=4096, D=1024, DK=DV=128.
// ws layout: Qb[16384][128]bf16 @0 (4MB) | Kb @4MB | Vt[B][128][4096]bf16 @8MB
//            | Wtq bf16[128][1024] @12MB | Wtk | Wtv (ends 12.75MB)
//            | Po[nsplit][16384][128]f32 @13MB | ml[nsplit][16384][2]f32 after.

typedef __bf16 bf16x8 __attribute__((ext_vector_type(8)));
typedef float f32x4 __attribute__((ext_vector_type(4)));
typedef float f32x16 __attribute__((ext_vector_type(16)));

typedef const __attribute__((address_space(1))) unsigned int* gp_t;
typedef __attribute__((address_space(3))) unsigned int* lp_t;

__device__ __forceinline__ unsigned short f2bf(float f) {
  unsigned u = __float_as_uint(f);
  u += 0x7fffu + ((u >> 16) & 1u);   // RNE
  return (unsigned short)(u >> 16);
}

__device__ __forceinline__ bf16x8 ld_frag(const char* p) {
  uint4 u = *reinterpret_cast<const uint4*>(p);
  return __builtin_bit_cast(bf16x8, u);
}

__device__ __forceinline__ unsigned cvtpk_bf16(float lo, float hi) {
  unsigned r;
  asm("v_cvt_pk_bf16_f32 %0, %1, %2" : "=v"(r) : "v"(lo), "v"(hi));
  return r;
}

__device__ __forceinline__ void pl32swap(unsigned &a, unsigned &b) {
  asm("v_permlane32_swap_b32 %0, %1" : "+v"(a), "+v"(b));
}

__device__ __forceinline__ bf16x8 mk_frag(unsigned w0, unsigned w1, unsigned w2, unsigned w3) {
  uint4 u{w0, w1, w2, w3};
  return __builtin_bit_cast(bf16x8, u);
}

__device__ __forceinline__ bf16x8 cvt_frag(const float4& f0, const float4& f1) {
  return mk_frag(cvtpk_bf16(f0.x, f0.y), cvtpk_bf16(f0.z, f0.w),
                 cvtpk_bf16(f1.x, f1.y), cvtpk_bf16(f1.z, f1.w));
}

// Q is pre-scaled by (1/sqrt(128)) * log2(e) so softmax uses exp2 directly.
#define QSCALE_LOG2E 0.12751744f

// ---------------- W transpose: [1024][128] f32 -> [128][1024] bf16 ----------
__global__ __launch_bounds__(256) void prep_wt_kernel(
    const float* __restrict__ W0, const float* __restrict__ W1, const float* __restrict__ W2,
    unsigned short* __restrict__ T0, unsigned short* __restrict__ T1,
    unsigned short* __restrict__ T2) {
  const int mode = blockIdx.z;
  const float* W = (mode == 0) ? W0 : (mode == 1) ? W1 : W2;
  unsigned short* Wt = (mode == 0) ? T0 : (mode == 1) ? T1 : T2;
  __shared__ float tile[64][65];
  int kt = blockIdx.x, nt = blockIdx.y;   // (16, 2)
  int tid = threadIdx.x;
  int c = tid & 63;
  int r0 = (tid >> 6) * 16;
#pragma unroll
  for (int i = 0; i < 16; ++i) {
    int r = r0 + i;
    tile[r][c] = W[(size_t)(kt * 64 + r) * 128 + nt * 64 + c];
  }
  __syncthreads();
#pragma unroll
  for (int i = 0; i < 16; ++i) {
    int n = r0 + i;
    Wt[(size_t)(nt * 64 + n) * 1024 + kt * 64 + c] = f2bf(tile[c][n]);
  }
}

// ---------------- projections: X[16384][1024]f32 @ Wt -> bf16 outputs -------
// BM=128, 8 waves; each wave owns 16 M-rows x all 128 N-cols.
// A: global->reg direct (no LDS), reg double-buffer, fully unrolled K-loop.
// W: global_load_lds w16, 3-deep LDS rotation, inverse-swizzled source.
// One barrier + counted vmcnt(2) per K-step.
__global__ __launch_bounds__(512, 4) void proj_kernel(
    const float* __restrict__ qx, const float* __restrict__ kx, const float* __restrict__ vx,
    const unsigned short* __restrict__ Wtq, const unsigned short* __restrict__ Wtk,
    const unsigned short* __restrict__ Wtv,
    const float* __restrict__ bq, const float* __restrict__ bk, const float* __restrict__ bv,
    unsigned short* __restrict__ Qb, unsigned short* __restrict__ Kb,
    unsigned short* __restrict__ Vtb) {
  const int mode = blockIdx.y;  // 0=Q 1=K 2=V
  const float* x = (mode == 0) ? qx : (mode == 1) ? kx : vx;
  const unsigned short* Wt = (mode == 0) ? Wtq : (mode == 1) ? Wtk : Wtv;
  const float* bias = (mode == 0) ? bq : (mode == 1) ? bk : bv;

  __shared__ __align__(16) char ldsW[49152];  // 3 x 16KB W tiles (128 rows x 64 k bf16)

  const int tid = threadIdx.x;
  const int lane = tid & 63, wid = tid >> 6;   // 8 waves
  const int l15 = lane & 15, hi = lane >> 4;
  const long row0 = (long)blockIdx.x * 128;

  // A: lane reads row (row0 + wid*16 + l15), k = t*64 + kk*32 + hi*8 (2 float4 per kk)
  const float* a_base = x + (row0 + wid * 16 + l15) * 1024 + hi * 8;

  // W staging: thread stages 2x16B. Linear LDS byte = i*8192 + tid*16 ->
  // row = i*64 + (tid>>3), col16 = tid&7. Source col pre-swizzled (involution).
  const char* w_src = (const char*)Wt + (size_t)(tid >> 3) * 2048 +
                      (size_t)((tid & 7) ^ ((tid >> 3) & 7)) * 16;

  f32x4 acc[8];
#pragma unroll
  for (int i = 0; i < 8; ++i) acc[i] = f32x4{0.f, 0.f, 0.f, 0.f};

  float4 aA[4], aB[4];  // [kk*2+h]

#define PROJ_STAGE_W(TS)                                                              \
  {                                                                                   \
    char* lw_ = ldsW + ((TS) % 3) * 16384;                                            \
    _Pragma("unroll")                                                                 \
    for (int i = 0; i < 2; ++i)                                                       \
      __builtin_amdgcn_global_load_lds((gp_t)(w_src + (size_t)i * 131072 + (TS) * 128),\
                                       (lp_t)(lw_ + i * 8192 + wid * 1024), 16, 0, 0);\
  }

  // prologue: A(0) -> aA, stage W(0), W(1)
#pragma unroll
  for (int kk = 0; kk < 2; ++kk)
#pragma unroll
    for (int h = 0; h < 2; ++h)
      aA[kk * 2 + h] = *reinterpret_cast<const float4*>(a_base + kk * 32 + h * 4);
  PROJ_STAGE_W(0);
  PROJ_STAGE_W(1);

#define PROJ_ITER(T, CUR, NXT)                                                        \
  {                                                                                   \
    if ((T) < 15) asm volatile("s_waitcnt vmcnt(2)" ::: "memory");                    \
    else          asm volatile("s_waitcnt vmcnt(0)" ::: "memory");                    \
    __builtin_amdgcn_s_barrier();                                                     \
    __builtin_amdgcn_sched_barrier(0);                                                \
    if ((T) < 15) {                                                                   \
      _Pragma("unroll")                                                               \
      for (int kk = 0; kk < 2; ++kk)                                                  \
        _Pragma("unroll")                                                             \
        for (int h = 0; h < 2; ++h)                                                   \
          NXT[kk * 2 + h] = *reinterpret_cast<const float4*>(                         \
              a_base + ((T) + 1) * 64 + kk * 32 + h * 4);                             \
    }                                                                                 \
    if ((T) < 14) PROJ_STAGE_W((T) + 2);                                              \
    bf16x8 af0 = cvt_frag(CUR[0], CUR[1]);                                            \
    bf16x8 af1 = cvt_frag(CUR[2], CUR[3]);                                            \
    char* lwc_ = ldsW + ((T) % 3) * 16384;                                            \
    __builtin_amdgcn_s_setprio(1);                                                    \
    _Pragma("unroll")                                                                 \
    for (int ni = 0; ni < 8; ++ni) {                                                  \
      int row = ni * 16 + l15;                                                        \
      int swz = (row & 7) << 4;                                                       \
      bf16x8 wf0 = ld_frag(lwc_ + ((row * 128 + hi * 16) ^ swz));                     \
      bf16x8 wf1 = ld_frag(lwc_ + ((row * 128 + 64 + hi * 16) ^ swz));                \
      acc[ni] = __builtin_amdgcn_mfma_f32_16x16x32_bf16(af0, wf0, acc[ni], 0, 0, 0);  \
      acc[ni] = __builtin_amdgcn_mfma_f32_16x16x32_bf16(af1, wf1, acc[ni], 0, 0, 0);  \
    }                                                                                 \
    __builtin_amdgcn_s_setprio(0);                                                    \
  }

#pragma unroll
  for (int t = 0; t < 16; ++t) {
    if (t & 1) PROJ_ITER(t, aB, aA)
    else       PROJ_ITER(t, aA, aB)
  }

#undef PROJ_ITER
#undef PROJ_STAGE_W

  // epilogue: +bias, (Q: * scale), store. C: col(n16)=l15, row = hi*4 + reg.
#pragma unroll
  for (int ni = 0; ni < 8; ++ni) {
    int n = ni * 16 + l15;
    float bv_ = bias[n];
    long m = row0 + wid * 16 + hi * 4;
    f32x4 a = acc[ni];
    if (mode == 2) {
      int bb = (int)(m >> 12);
      int s = (int)(m & 4095);
      ushort4 pk;
      pk.x = f2bf(a.x + bv_); pk.y = f2bf(a.y + bv_);
      pk.z = f2bf(a.z + bv_); pk.w = f2bf(a.w + bv_);
      *reinterpret_cast<ushort4*>(Vtb + ((size_t)(bb * 128 + n)) * 4096 + s) = pk;
    } else {
      const float sc = (mode == 0) ? QSCALE_LOG2E : 1.0f;
      unsigned short* outp = (mode == 0) ? Qb : Kb;
      outp[(m + 0) * 128 + n] = f2bf((a.x + bv_) * sc);
      outp[(m + 1) * 128 + n] = f2bf((a.y + bv_) * sc);
      outp[(m + 2) * 128 + n] = f2bf((a.z + bv_) * sc);
      outp[(m + 3) * 128 + n] = f2bf((a.w + bv_) * sc);
    }
  }
}

// ---------------- flash attention (32x32 swapped-operand, KV-split) ---------
__global__ __launch_bounds__(256, 2) void attn_kernel(
    const unsigned short* __restrict__ Qb, const unsigned short* __restrict__ Kb,
    const unsigned short* __restrict__ Vtb, float* __restrict__ Po,
    float* __restrict__ ml, int tps) {
  __shared__ uint4 ldsK4[1024];  // 64 kv-rows x 128 d bf16, swizzled (16KB)
  __shared__ uint4 ldsV4[1024];  // 128 dv-rows x 64 k bf16, swizzled (16KB)
  char* ldsK = (char*)ldsK4;
  char* ldsV = (char*)ldsV4;

  const int tid = threadIdx.x;
  const int lane = tid & 63, wid = tid >> 6;
  const int l31 = lane & 31, hi = lane >> 5;
  const int split = blockIdx.y;
  const int b = blockIdx.z;
  const int qbase = blockIdx.x * 128 + wid * 32;  // within batch
  const size_t growq = (size_t)b * 4096 + qbase + l31;

  // Q fragments (B-operand): qf[kt] elem e <-> d = kt*16 + hi*8 + e
  bf16x8 qf[8];
  {
    const unsigned short* qp = Qb + growq * 128 + hi * 8;
#pragma unroll
    for (int kt = 0; kt < 8; ++kt)
      qf[kt] = __builtin_bit_cast(bf16x8, *reinterpret_cast<const uint4*>(qp + kt * 16));
  }

  f32x16 oacc[4];
#pragma unroll
  for (int d = 0; d < 4; ++d)
#pragma unroll
    for (int j = 0; j < 16; ++j) oacc[d][j] = 0.f;
  float mrun = -INFINITY, lrun = 0.f;

  const int t0 = split * tps, t1 = t0 + tps;

  for (int t = t0; t < t1; ++t) {
    const int kv0 = t * 64;
    const char* kg = (const char*)Kb + ((size_t)(b * 4096) + kv0) * 256;
#pragma unroll
    for (int i = 0; i < 4; ++i) {
      int u = tid + 256 * i;
      int row = u >> 4, c = u & 15;
      uint4 val = *reinterpret_cast<const uint4*>(kg + row * 256 + c * 16);
      *reinterpret_cast<uint4*>(ldsK + ((row * 256 + c * 16) ^ ((row & 7) << 4))) = val;
    }
    const char* vg = (const char*)Vtb + (size_t)b * 128 * 4096 * 2 + (size_t)kv0 * 2;
#pragma unroll
    for (int i = 0; i < 4; ++i) {
      int u = tid + 256 * i;
      int dv = u >> 3, c = u & 7;
      uint4 val = *reinterpret_cast<const uint4*>(vg + (size_t)dv * 8192 + c * 16);
      *reinterpret_cast<uint4*>(ldsV + ((dv * 128 + c * 16) ^ ((dv & 7) << 4))) = val;
    }
    __syncthreads();

    // ---- QK^T (swapped): sc_c[reg] = S[kv = (reg&3)+8*(reg>>2)+4*hi + 32c][q = l31]
    f32x16 sc0, sc1;
#pragma unroll
    for (int j = 0; j < 16; ++j) { sc0[j] = 0.f; sc1[j] = 0.f; }
    __builtin_amdgcn_s_setprio(1);
#pragma unroll
    for (int kvb = 0; kvb < 2; ++kvb) {
      int row = kvb * 32 + l31;
      int rowoff = row * 256, swz = (row & 7) << 4;
#pragma unroll
      for (int kt = 0; kt < 8; ++kt) {
        bf16x8 kf = ld_frag(ldsK + ((rowoff + kt * 32 + hi * 16) ^ swz));
        if (kvb == 0) sc0 = __builtin_amdgcn_mfma_f32_32x32x16_bf16(kf, qf[kt], sc0, 0, 0, 0);
        else          sc1 = __builtin_amdgcn_mfma_f32_32x32x16_bf16(kf, qf[kt], sc1, 0, 0, 0);
      }
    }
    __builtin_amdgcn_s_setprio(0);

    // ---- online softmax, fully per-lane (q = l31)
    float tmx[16];
#pragma unroll
    for (int i = 0; i < 16; ++i) tmx[i] = fmaxf(sc0[i], sc1[i]);
#pragma unroll
    for (int s = 8; s > 0; s >>= 1)
#pragma unroll
      for (int i = 0; i < s; ++i) tmx[i] = fmaxf(tmx[i], tmx[i + s]);
    float mt = tmx[0];
    mt = fmaxf(mt, __shfl_xor(mt, 32));

    // defer-max (T13)
    if (!__all(mt - mrun <= 8.0f)) {
      float mnew = fmaxf(mrun, mt);
      float scl = exp2f(mrun - mnew);
      mrun = mnew;
      lrun *= scl;
#pragma unroll
      for (int d = 0; d < 4; ++d)
#pragma unroll
        for (int j = 0; j < 16; ++j) oacc[d][j] *= scl;
    }

    // P = exp2(S - m) in-register
#pragma unroll
    for (int i = 0; i < 16; ++i) {
      sc0[i] = exp2f(sc0[i] - mrun);
      sc1[i] = exp2f(sc1[i] - mrun);
    }
    float ts[16];
#pragma unroll
    for (int i = 0; i < 16; ++i) ts[i] = sc0[i] + sc1[i];
#pragma unroll
    for (int s = 8; s > 0; s >>= 1)
#pragma unroll
      for (int i = 0; i < s; ++i) ts[i] += ts[i + s];
    float psum = ts[0];
    psum += __shfl_xor(psum, 32);
    lrun += psum;

    // ---- P -> bf16 fragments via cvt_pk + permlane32_swap (T12)
    bf16x8 pa[4];
#pragma unroll
    for (int c = 0; c < 2; ++c) {
      const f32x16& p = c ? sc1 : sc0;
#pragma unroll
      for (int g = 0; g < 2; ++g) {
        const int base = g * 8;
        unsigned a0 = cvtpk_bf16(p[base + 0], p[base + 1]);
        unsigned b0 = cvtpk_bf16(p[base + 4], p[base + 5]);
        pl32swap(a0, b0);
        unsigned a1 = cvtpk_bf16(p[base + 2], p[base + 3]);
        unsigned b1 = cvtpk_bf16(p[base + 6], p[base + 7]);
        pl32swap(a1, b1);
        pa[c * 2 + g] = mk_frag(a0, a1, b0, b1);
      }
    }

    // ---- PV (swapped): oacc[dvb] += mfma(A=Vt rows, B=P^T)
    __builtin_amdgcn_s_setprio(1);
#pragma unroll
    for (int dvb = 0; dvb < 4; ++dvb) {
      int vrow = dvb * 32 + l31;
      int voff = vrow * 128, vswz = (vrow & 7) << 4;
#pragma unroll
      for (int tt = 0; tt < 4; ++tt) {
        bf16x8 vf = ld_frag(ldsV + ((voff + tt * 32 + hi * 16) ^ vswz));
        oacc[dvb] = __builtin_amdgcn_mfma_f32_32x32x16_bf16(vf, pa[tt], oacc[dvb], 0, 0, 0);
      }
    }
    __builtin_amdgcn_s_setprio(0);
    __syncthreads();
  }

  // ---- epilogue: ml + O^T -> O via per-wave LDS transpose, coalesced stores
  if (hi == 0) {
    float* mlp = ml + (size_t)split * 32768 + growq * 2;
    mlp[0] = mrun; mlp[1] = lrun;
  }

  float* po = Po + ((size_t)split << 21) + ((size_t)b * 4096 + qbase) * 128;
  char* tbase = ldsK + wid * 4096;  // 32q x 32dv f32 = 4KB per wave
  for (int dvb = 0; dvb < 4; ++dvb) {
#pragma unroll
    for (int g = 0; g < 4; ++g) {
      float4 w4{oacc[dvb][g * 4 + 0], oacc[dvb][g * 4 + 1],
                oacc[dvb][g * 4 + 2], oacc[dvb][g * 4 + 3]};
      int off = (l31 * 128 + g * 32 + hi * 16) ^ ((l31 & 7) << 4);
      *reinterpret_cast<float4*>(tbase + off) = w4;
    }
    asm volatile("s_waitcnt lgkmcnt(0)" ::: "memory");
    __builtin_amdgcn_sched_barrier(0);
#pragma unroll
    for (int qq = 0; qq < 4; ++qq) {
      int q = qq * 8 + (lane >> 3);
      int off = (q * 128 + (lane & 7) * 16) ^ ((q & 7) << 4);
      float4 r4 = *reinterpret_cast<const float4*>(tbase + off);
      *reinterpret_cast<float4*>(po + (size_t)q * 128 + dvb * 32 + (lane & 7) * 4) = r4;
    }
    asm volatile("s_waitcnt lgkmcnt(0)" ::: "memory");
    __builtin_amdgcn_sched_barrier(0);
  }
}

// ---------------- combine partials ------------------------------------------
template <int NS>
__global__ __launch_bounds__(256) void combine_kernel(const float* __restrict__ Po,
                                                      const float* __restrict__ ml,
                                                      float* __restrict__ out) {
  int idx = blockIdx.x * 256 + threadIdx.x;  // 16384*32 float4-units
  int grow = idx >> 5;
  int c4 = (idx & 31) * 4;
  float m[NS], l[NS];
  float M = -INFINITY;
#pragma unroll
  for (int s = 0; s < NS; ++s) {
    m[s] = ml[(size_t)s * 32768 + grow * 2 + 0];
    l[s] = ml[(size_t)s * 32768 + grow * 2 + 1];
    M = fmaxf(M, m[s]);
  }
  float L = 0.f, w[NS];
#pragma unroll
  for (int s = 0; s < NS; ++s) {
    w[s] = exp2f(m[s] - M);   // log2 domain
    L += l[s] * w[s];
  }
  float invL = 1.0f / L;
  float4 acc = {0.f, 0.f, 0.f, 0.f};
#pragma unroll
  for (int s = 0; s < NS; ++s) {
    float4 p = *reinterpret_cast<const float4*>(Po + ((size_t)s << 21) + (size_t)grow * 128 + c4);
    acc.x += p.x * w[s]; acc.y += p.y * w[s];
    acc.z += p.z * w[s]; acc.w += p.w * w[s];
  }
  acc.x *= invL; acc.y *= invL; acc.z *= invL; acc.w *= invL;
  *reinterpret_cast<float4*>(out + (size_t)grow * 128 + c4) = acc;
}

extern "C" void kernel_launch(void* const* d_in, const int* in_sizes, int n_in,
                              void* d_out, int out_size, void* d_ws, size_t ws_size,
                              hipStream_t stream) {
  const float* q  = (const float*)d_in[0];
  const float* k  = (const float*)d_in[1];
  const float* v  = (const float*)d_in[2];
  const float* Wq = (const float*)d_in[3];
  const float* bq = (const float*)d_in[4];
  const float* Wk = (const float*)d_in[5];
  const float* bk = (const float*)d_in[6];
  const float* Wv = (const float*)d_in[7];
  const float* bv = (const float*)d_in[8];
  float* out = (float*)d_out;

  char* ws = (char*)d_ws;
  unsigned short* Qb  = (unsigned short*)(ws);
  unsigned short* Kb  = (unsigned short*)(ws + (4u << 20));
  unsigned short* Vtb = (unsigned short*)(ws + (8u << 20));
  unsigned short* Wtq = (unsigned short*)(ws + (12u << 20));
  unsigned short* Wtk = (unsigned short*)(ws + (12u << 20) + (256u << 10));
  unsigned short* Wtv = (unsigned short*)(ws + (12u << 20) + (512u << 10));

  const size_t base = (size_t)13 << 20;
  const size_t per = ((size_t)8 << 20) + ((size_t)128 << 10);
  int nsplit = 1;
  if (ws_size >= base + 4 * per) nsplit = 4;
  else if (ws_size >= base + 2 * per) nsplit = 2;
  float* Po = (float*)(ws + base);
  float* ml = (float*)(ws + base + (size_t)nsplit * ((size_t)8 << 20));

  prep_wt_kernel<<<dim3(16, 2, 3), 256, 0, stream>>>(Wq, Wk, Wv, Wtq, Wtk, Wtv);
  proj_kernel<<<dim3(128, 3), 512, 0, stream>>>(q, k, v, Wtq, Wtk, Wtv, bq, bk, bv, Qb, Kb, Vtb);
  attn_kernel<<<dim3(32, nsplit, 4), 256, 0, stream>>>(Qb, Kb, Vtb, Po, ml, 64 / nsplit);
  if (nsplit == 4)      combine_kernel<4><<<2048, 256, 0, stream>>>(Po, ml, out);
  else if (nsplit == 2) combine_kernel<2><<<2048, 256, 0, stream>>>(Po, ml, out);
  else                  combine_kernel<1><<<2048, 256, 0, stream>>>(Po, ml, out);
}

// Round 9
// 103.647 us; speedup vs baseline: 1.6950x; 1.0149x over previous
//
#include <hip/hip_runtime.h>
#include <hip/hip_bf16.h>
#include <cstdint>
#include <cmath>

// Shapes (hard-coded): B=4, S=4096, D=1024, DK=DV=128.
// ws layout: Qb[16384][128]bf16 @0 (4MB) | Kb @4MB | Vt[B][128][4096]bf16 @8MB
//            | Wtq bf16[128][1024] @12MB | Wtk | Wtv (ends 12.75MB)
//            | Po[nsplit][16384][128]f32 @13MB | ml[nsplit][16384][2]f32 after.

typedef __bf16 bf16x8 __attribute__((ext_vector_type(8)));
typedef float f32x4 __attribute__((ext_vector_type(4)));
typedef float f32x16 __attribute__((ext_vector_type(16)));

typedef const __attribute__((address_space(1))) unsigned int* gp_t;
typedef __attribute__((address_space(3))) unsigned int* lp_t;

__device__ __forceinline__ unsigned short f2bf(float f) {
  unsigned u = __float_as_uint(f);
  u += 0x7fffu + ((u >> 16) & 1u);   // RNE
  return (unsigned short)(u >> 16);
}

__device__ __forceinline__ bf16x8 ld_frag(const char* p) {
  uint4 u = *reinterpret_cast<const uint4*>(p);
  return __builtin_bit_cast(bf16x8, u);
}

__device__ __forceinline__ unsigned cvtpk_bf16(float lo, float hi) {
  unsigned r;
  asm("v_cvt_pk_bf16_f32 %0, %1, %2" : "=v"(r) : "v"(lo), "v"(hi));
  return r;
}

__device__ __forceinline__ void pl32swap(unsigned &a, unsigned &b) {
  asm("v_permlane32_swap_b32 %0, %1" : "+v"(a), "+v"(b));
}

__device__ __forceinline__ bf16x8 mk_frag(unsigned w0, unsigned w1, unsigned w2, unsigned w3) {
  uint4 u{w0, w1, w2, w3};
  return __builtin_bit_cast(bf16x8, u);
}

__device__ __forceinline__ bf16x8 cvt_frag(const float4& f0, const float4& f1) {
  return mk_frag(cvtpk_bf16(f0.x, f0.y), cvtpk_bf16(f0.z, f0.w),
                 cvtpk_bf16(f1.x, f1.y), cvtpk_bf16(f1.z, f1.w));
}

// Q is pre-scaled by (1/sqrt(128)) * log2(e) so softmax uses exp2 directly.
#define QSCALE_LOG2E 0.12751744f

// ---------------- W transpose: [1024][128] f32 -> [128][1024] bf16 ----------
__global__ __launch_bounds__(256) void prep_wt_kernel(
    const float* __restrict__ W0, const float* __restrict__ W1, const float* __restrict__ W2,
    unsigned short* __restrict__ T0, unsigned short* __restrict__ T1,
    unsigned short* __restrict__ T2) {
  const int mode = blockIdx.z;
  const float* W = (mode == 0) ? W0 : (mode == 1) ? W1 : W2;
  unsigned short* Wt = (mode == 0) ? T0 : (mode == 1) ? T1 : T2;
  __shared__ float tile[64][65];
  int kt = blockIdx.x, nt = blockIdx.y;   // (16, 2)
  int tid = threadIdx.x;
  int c = tid & 63;
  int r0 = (tid >> 6) * 16;
#pragma unroll
  for (int i = 0; i < 16; ++i) {
    int r = r0 + i;
    tile[r][c] = W[(size_t)(kt * 64 + r) * 128 + nt * 64 + c];
  }
  __syncthreads();
#pragma unroll
  for (int i = 0; i < 16; ++i) {
    int n = r0 + i;
    Wt[(size_t)(nt * 64 + n) * 1024 + kt * 64 + c] = f2bf(tile[c][n]);
  }
}

// ---------------- projections (round-8 version, timed ~floor) ---------------
__global__ __launch_bounds__(512, 4) void proj_kernel(
    const float* __restrict__ qx, const float* __restrict__ kx, const float* __restrict__ vx,
    const unsigned short* __restrict__ Wtq, const unsigned short* __restrict__ Wtk,
    const unsigned short* __restrict__ Wtv,
    const float* __restrict__ bq, const float* __restrict__ bk, const float* __restrict__ bv,
    unsigned short* __restrict__ Qb, unsigned short* __restrict__ Kb,
    unsigned short* __restrict__ Vtb) {
  const int mode = blockIdx.y;  // 0=Q 1=K 2=V
  const float* x = (mode == 0) ? qx : (mode == 1) ? kx : vx;
  const unsigned short* Wt = (mode == 0) ? Wtq : (mode == 1) ? Wtk : Wtv;
  const float* bias = (mode == 0) ? bq : (mode == 1) ? bk : bv;

  __shared__ __align__(16) char ldsW[49152];  // 3 x 16KB W tiles

  const int tid = threadIdx.x;
  const int lane = tid & 63, wid = tid >> 6;   // 8 waves
  const int l15 = lane & 15, hi = lane >> 4;
  const long row0 = (long)blockIdx.x * 128;

  const float* a_base = x + (row0 + wid * 16 + l15) * 1024 + hi * 8;
  const char* w_src = (const char*)Wt + (size_t)(tid >> 3) * 2048 +
                      (size_t)((tid & 7) ^ ((tid >> 3) & 7)) * 16;

  f32x4 acc[8];
#pragma unroll
  for (int i = 0; i < 8; ++i) acc[i] = f32x4{0.f, 0.f, 0.f, 0.f};

  float4 aA[4], aB[4];

#define PROJ_STAGE_W(TS)                                                              \
  {                                                                                   \
    char* lw_ = ldsW + ((TS) % 3) * 16384;                                            \
    _Pragma("unroll")                                                                 \
    for (int i = 0; i < 2; ++i)                                                       \
      __builtin_amdgcn_global_load_lds((gp_t)(w_src + (size_t)i * 131072 + (TS) * 128),\
                                       (lp_t)(lw_ + i * 8192 + wid * 1024), 16, 0, 0);\
  }

#pragma unroll
  for (int kk = 0; kk < 2; ++kk)
#pragma unroll
    for (int h = 0; h < 2; ++h)
      aA[kk * 2 + h] = *reinterpret_cast<const float4*>(a_base + kk * 32 + h * 4);
  PROJ_STAGE_W(0);
  PROJ_STAGE_W(1);

#define PROJ_ITER(T, CUR, NXT)                                                        \
  {                                                                                   \
    if ((T) < 15) asm volatile("s_waitcnt vmcnt(2)" ::: "memory");                    \
    else          asm volatile("s_waitcnt vmcnt(0)" ::: "memory");                    \
    __builtin_amdgcn_s_barrier();                                                     \
    __builtin_amdgcn_sched_barrier(0);                                                \
    if ((T) < 15) {                                                                   \
      _Pragma("unroll")                                                               \
      for (int kk = 0; kk < 2; ++kk)                                                  \
        _Pragma("unroll")                                                             \
        for (int h = 0; h < 2; ++h)                                                   \
          NXT[kk * 2 + h] = *reinterpret_cast<const float4*>(                         \
              a_base + ((T) + 1) * 64 + kk * 32 + h * 4);                             \
    }                                                                                 \
    if ((T) < 14) PROJ_STAGE_W((T) + 2);                                              \
    bf16x8 af0 = cvt_frag(CUR[0], CUR[1]);                                            \
    bf16x8 af1 = cvt_frag(CUR[2], CUR[3]);                                            \
    char* lwc_ = ldsW + ((T) % 3) * 16384;                                            \
    __builtin_amdgcn_s_setprio(1);                                                    \
    _Pragma("unroll")                                                                 \
    for (int ni = 0; ni < 8; ++ni) {                                                  \
      int row = ni * 16 + l15;                                                        \
      int swz = (row & 7) << 4;                                                       \
      bf16x8 wf0 = ld_frag(lwc_ + ((row * 128 + hi * 16) ^ swz));                     \
      bf16x8 wf1 = ld_frag(lwc_ + ((row * 128 + 64 + hi * 16) ^ swz));                \
      acc[ni] = __builtin_amdgcn_mfma_f32_16x16x32_bf16(af0, wf0, acc[ni], 0, 0, 0);  \
      acc[ni] = __builtin_amdgcn_mfma_f32_16x16x32_bf16(af1, wf1, acc[ni], 0, 0, 0);  \
    }                                                                                 \
    __builtin_amdgcn_s_setprio(0);                                                    \
  }

#pragma unroll
  for (int t = 0; t < 16; ++t) {
    if (t & 1) PROJ_ITER(t, aB, aA)
    else       PROJ_ITER(t, aA, aB)
  }

#undef PROJ_ITER
#undef PROJ_STAGE_W

#pragma unroll
  for (int ni = 0; ni < 8; ++ni) {
    int n = ni * 16 + l15;
    float bv_ = bias[n];
    long m = row0 + wid * 16 + hi * 4;
    f32x4 a = acc[ni];
    if (mode == 2) {
      int bb = (int)(m >> 12);
      int s = (int)(m & 4095);
      ushort4 pk;
      pk.x = f2bf(a.x + bv_); pk.y = f2bf(a.y + bv_);
      pk.z = f2bf(a.z + bv_); pk.w = f2bf(a.w + bv_);
      *reinterpret_cast<ushort4*>(Vtb + ((size_t)(bb * 128 + n)) * 4096 + s) = pk;
    } else {
      const float sc = (mode == 0) ? QSCALE_LOG2E : 1.0f;
      unsigned short* outp = (mode == 0) ? Qb : Kb;
      outp[(m + 0) * 128 + n] = f2bf((a.x + bv_) * sc);
      outp[(m + 1) * 128 + n] = f2bf((a.y + bv_) * sc);
      outp[(m + 2) * 128 + n] = f2bf((a.z + bv_) * sc);
      outp[(m + 3) * 128 + n] = f2bf((a.w + bv_) * sc);
    }
  }
}

// ---------------- flash attention (32x32 swapped, dbuf K/V + counted vmcnt) -
// K/V staged via global_load_lds w16: linear LDS dest + pre-swizzled global
// source (involution matches the XOR-swizzled read side). 2-deep pipeline:
// wait vmcnt(8) [tile t ready, t+1 in flight]; barrier; compute; barrier;
// stage(t+2). Never drains vmcnt to 0 in the main loop (T3/T4).
template <int TPS>
__global__ __launch_bounds__(256, 2) void attn_kernel(
    const unsigned short* __restrict__ Qb, const unsigned short* __restrict__ Kb,
    const unsigned short* __restrict__ Vtb, float* __restrict__ Po,
    float* __restrict__ ml) {
  __shared__ __align__(16) char lds[65536];  // K: 2x16KB @0, V: 2x16KB @32768

  const int tid = threadIdx.x;
  const int lane = tid & 63, wid = tid >> 6;
  const int l31 = lane & 31, hi = lane >> 5;
  const int split = blockIdx.y;
  const int b = blockIdx.z;
  const int qbase = blockIdx.x * 128 + wid * 32;  // within batch
  const size_t growq = (size_t)b * 4096 + qbase + l31;

  // staging address prep (constant per thread)
  const char* kg0 = (const char*)Kb + (size_t)(b * 4096) * 256;    // + kv0*256
  const char* vg0 = (const char*)Vtb + (size_t)b * 128 * 4096 * 2; // + kv0*2
  // K: dest linear ofs = i*4096 + tid*16 -> row = i*16 + (tid>>4), c = tid&15
  const int k_row = tid >> 4;                                  // + i*16
  const int k_csw = (tid & 15) ^ (k_row & 7);
  // V: dest linear ofs = i*4096 + tid*16 -> dv = i*32 + (tid>>3), c = tid&7
  const int v_dv = tid >> 3;                                   // + i*32
  const int v_csw = (tid & 7) ^ (v_dv & 7);

#define ATTN_STAGE(KV0, BUF)                                                          \
  {                                                                                   \
    char* kb_ = lds + (BUF) * 16384;                                                  \
    char* vb_ = lds + 32768 + (BUF) * 16384;                                          \
    const char* kgs_ = kg0 + (size_t)(KV0) * 256 + (size_t)k_row * 256 + k_csw * 16;  \
    const char* vgs_ = vg0 + (size_t)(KV0) * 2 + (size_t)v_dv * 8192 + v_csw * 16;    \
    _Pragma("unroll")                                                                 \
    for (int i = 0; i < 4; ++i)                                                       \
      __builtin_amdgcn_global_load_lds((gp_t)(kgs_ + (size_t)i * 4096),               \
                                       (lp_t)(kb_ + i * 4096 + wid * 1024), 16, 0, 0);\
    _Pragma("unroll")                                                                 \
    for (int i = 0; i < 4; ++i)                                                       \
      __builtin_amdgcn_global_load_lds((gp_t)(vgs_ + (size_t)i * 262144),             \
                                       (lp_t)(vb_ + i * 4096 + wid * 1024), 16, 0, 0);\
  }

  // hoist Q fragments (B-operand): qf[kt] elem e <-> d = kt*16 + hi*8 + e
  bf16x8 qf[8];
  {
    const unsigned short* qp = Qb + growq * 128 + hi * 8;
#pragma unroll
    for (int kt = 0; kt < 8; ++kt)
      qf[kt] = __builtin_bit_cast(bf16x8, *reinterpret_cast<const uint4*>(qp + kt * 16));
  }

  f32x16 oacc[4];
#pragma unroll
  for (int d = 0; d < 4; ++d)
#pragma unroll
    for (int j = 0; j < 16; ++j) oacc[d][j] = 0.f;
  float mrun = -INFINITY, lrun = 0.f;

  const int t0 = split * TPS, t1 = t0 + TPS;

  // prologue: 2 tiles in flight
  ATTN_STAGE(t0 * 64, 0);
  ATTN_STAGE((t0 + 1) * 64, 1);

#pragma unroll 1
  for (int t = t0; t < t1; ++t) {
    const int buf = (t - t0) & 1;
    if (t < t1 - 1) asm volatile("s_waitcnt vmcnt(8)" ::: "memory");
    else            asm volatile("s_waitcnt vmcnt(0)" ::: "memory");
    __builtin_amdgcn_s_barrier();
    __builtin_amdgcn_sched_barrier(0);
    char* ldsK = lds + buf * 16384;
    char* ldsV = lds + 32768 + buf * 16384;

    // ---- QK^T (swapped): sc_c[reg] = S[kv = (reg&3)+8*(reg>>2)+4*hi + 32c][q = l31]
    f32x16 sc0, sc1;
#pragma unroll
    for (int j = 0; j < 16; ++j) { sc0[j] = 0.f; sc1[j] = 0.f; }
    __builtin_amdgcn_s_setprio(1);
#pragma unroll
    for (int kvb = 0; kvb < 2; ++kvb) {
      int row = kvb * 32 + l31;
      int rowoff = row * 256, swz = (row & 7) << 4;
#pragma unroll
      for (int kt = 0; kt < 8; ++kt) {
        bf16x8 kf = ld_frag(ldsK + ((rowoff + kt * 32 + hi * 16) ^ swz));
        if (kvb == 0) sc0 = __builtin_amdgcn_mfma_f32_32x32x16_bf16(kf, qf[kt], sc0, 0, 0, 0);
        else          sc1 = __builtin_amdgcn_mfma_f32_32x32x16_bf16(kf, qf[kt], sc1, 0, 0, 0);
      }
    }
    __builtin_amdgcn_s_setprio(0);

    // ---- online softmax, fully per-lane (q = l31)
    float tmx[16];
#pragma unroll
    for (int i = 0; i < 16; ++i) tmx[i] = fmaxf(sc0[i], sc1[i]);
#pragma unroll
    for (int s = 8; s > 0; s >>= 1)
#pragma unroll
      for (int i = 0; i < s; ++i) tmx[i] = fmaxf(tmx[i], tmx[i + s]);
    float mt = tmx[0];
    mt = fmaxf(mt, __shfl_xor(mt, 32));

    // defer-max (T13)
    if (!__all(mt - mrun <= 8.0f)) {
      float mnew = fmaxf(mrun, mt);
      float scl = exp2f(mrun - mnew);
      mrun = mnew;
      lrun *= scl;
#pragma unroll
      for (int d = 0; d < 4; ++d)
#pragma unroll
        for (int j = 0; j < 16; ++j) oacc[d][j] *= scl;
    }

    // P = exp2(S - m) in-register
#pragma unroll
    for (int i = 0; i < 16; ++i) {
      sc0[i] = exp2f(sc0[i] - mrun);
      sc1[i] = exp2f(sc1[i] - mrun);
    }
    float ts[16];
#pragma unroll
    for (int i = 0; i < 16; ++i) ts[i] = sc0[i] + sc1[i];
#pragma unroll
    for (int s = 8; s > 0; s >>= 1)
#pragma unroll
      for (int i = 0; i < s; ++i) ts[i] += ts[i + s];
    float psum = ts[0];
    psum += __shfl_xor(psum, 32);
    lrun += psum;

    // ---- P -> bf16 fragments via cvt_pk + permlane32_swap (T12)
    bf16x8 pa[4];
#pragma unroll
    for (int c = 0; c < 2; ++c) {
      const f32x16& p = c ? sc1 : sc0;
#pragma unroll
      for (int g = 0; g < 2; ++g) {
        const int base = g * 8;
        unsigned a0 = cvtpk_bf16(p[base + 0], p[base + 1]);
        unsigned b0 = cvtpk_bf16(p[base + 4], p[base + 5]);
        pl32swap(a0, b0);
        unsigned a1 = cvtpk_bf16(p[base + 2], p[base + 3]);
        unsigned b1 = cvtpk_bf16(p[base + 6], p[base + 7]);
        pl32swap(a1, b1);
        pa[c * 2 + g] = mk_frag(a0, a1, b0, b1);
      }
    }

    // ---- PV (swapped): oacc[dvb] += mfma(A=Vt rows, B=P^T)
    __builtin_amdgcn_s_setprio(1);
#pragma unroll
    for (int dvb = 0; dvb < 4; ++dvb) {
      int vrow = dvb * 32 + l31;
      int voff = vrow * 128, vswz = (vrow & 7) << 4;
#pragma unroll
      for (int tt = 0; tt < 4; ++tt) {
        bf16x8 vf = ld_frag(ldsV + ((voff + tt * 32 + hi * 16) ^ vswz));
        oacc[dvb] = __builtin_amdgcn_mfma_f32_32x32x16_bf16(vf, pa[tt], oacc[dvb], 0, 0, 0);
      }
    }
    __builtin_amdgcn_s_setprio(0);

    __builtin_amdgcn_s_barrier();          // all waves done reading buf
    __builtin_amdgcn_sched_barrier(0);
    if (t + 2 < t1) ATTN_STAGE((t + 2) * 64, buf);
  }

#undef ATTN_STAGE

  // ---- epilogue: ml + O^T -> O via per-wave LDS transpose, coalesced stores
  if (hi == 0) {
    float* mlp = ml + (size_t)split * 32768 + growq * 2;
    mlp[0] = mrun; mlp[1] = lrun;
  }

  float* po = Po + ((size_t)split << 21) + ((size_t)b * 4096 + qbase) * 128;
  char* tbase = lds + wid * 4096;  // 32q x 32dv f32 = 4KB per wave
  for (int dvb = 0; dvb < 4; ++dvb) {
#pragma unroll
    for (int g = 0; g < 4; ++g) {
      float4 w4{oacc[dvb][g * 4 + 0], oacc[dvb][g * 4 + 1],
                oacc[dvb][g * 4 + 2], oacc[dvb][g * 4 + 3]};
      int off = (l31 * 128 + g * 32 + hi * 16) ^ ((l31 & 7) << 4);
      *reinterpret_cast<float4*>(tbase + off) = w4;
    }
    asm volatile("s_waitcnt lgkmcnt(0)" ::: "memory");
    __builtin_amdgcn_sched_barrier(0);
#pragma unroll
    for (int qq = 0; qq < 4; ++qq) {
      int q = qq * 8 + (lane >> 3);
      int off = (q * 128 + (lane & 7) * 16) ^ ((q & 7) << 4);
      float4 r4 = *reinterpret_cast<const float4*>(tbase + off);
      *reinterpret_cast<float4*>(po + (size_t)q * 128 + dvb * 32 + (lane & 7) * 4) = r4;
    }
    asm volatile("s_waitcnt lgkmcnt(0)" ::: "memory");
    __builtin_amdgcn_sched_barrier(0);
  }
}

// ---------------- combine partials ------------------------------------------
template <int NS>
__global__ __launch_bounds__(256) void combine_kernel(const float* __restrict__ Po,
                                                      const float* __restrict__ ml,
                                                      float* __restrict__ out) {
  int idx = blockIdx.x * 256 + threadIdx.x;  // 16384*32 float4-units
  int grow = idx >> 5;
  int c4 = (idx & 31) * 4;
  float m[NS], l[NS];
  float M = -INFINITY;
#pragma unroll
  for (int s = 0; s < NS; ++s) {
    m[s] = ml[(size_t)s * 32768 + grow * 2 + 0];
    l[s] = ml[(size_t)s * 32768 + grow * 2 + 1];
    M = fmaxf(M, m[s]);
  }
  float L = 0.f, w[NS];
#pragma unroll
  for (int s = 0; s < NS; ++s) {
    w[s] = exp2f(m[s] - M);   // log2 domain
    L += l[s] * w[s];
  }
  float invL = 1.0f / L;
  float4 acc = {0.f, 0.f, 0.f, 0.f};
#pragma unroll
  for (int s = 0; s < NS; ++s) {
    float4 p = *reinterpret_cast<const float4*>(Po + ((size_t)s << 21) + (size_t)grow * 128 + c4);
    acc.x += p.x * w[s]; acc.y += p.y * w[s];
    acc.z += p.z * w[s]; acc.w += p.w * w[s];
  }
  acc.x *= invL; acc.y *= invL; acc.z *= invL; acc.w *= invL;
  *reinterpret_cast<float4*>(out + (size_t)grow * 128 + c4) = acc;
}

extern "C" void kernel_launch(void* const* d_in, const int* in_sizes, int n_in,
                              void* d_out, int out_size, void* d_ws, size_t ws_size,
                              hipStream_t stream) {
  const float* q  = (const float*)d_in[0];
  const float* k  = (const float*)d_in[1];
  const float* v  = (const float*)d_in[2];
  const float* Wq = (const float*)d_in[3];
  const float* bq = (const float*)d_in[4];
  const float* Wk = (const float*)d_in[5];
  const float* bk = (const float*)d_in[6];
  const float* Wv = (const float*)d_in[7];
  const float* bv = (const float*)d_in[8];
  float* out = (float*)d_out;

  char* ws = (char*)d_ws;
  unsigned short* Qb  = (unsigned short*)(ws);
  unsigned short* Kb  = (unsigned short*)(ws + (4u << 20));
  unsigned short* Vtb = (unsigned short*)(ws + (8u << 20));
  unsigned short* Wtq = (unsigned short*)(ws + (12u << 20));
  unsigned short* Wtk = (unsigned short*)(ws + (12u << 20) + (256u << 10));
  unsigned short* Wtv = (unsigned short*)(ws + (12u << 20) + (512u << 10));

  const size_t base = (size_t)13 << 20;
  const size_t per = ((size_t)8 << 20) + ((size_t)128 << 10);
  int nsplit = 1;
  if (ws_size >= base + 4 * per) nsplit = 4;
  else if (ws_size >= base + 2 * per) nsplit = 2;
  float* Po = (float*)(ws + base);
  float* ml = (float*)(ws + base + (size_t)nsplit * ((size_t)8 << 20));

  prep_wt_kernel<<<dim3(16, 2, 3), 256, 0, stream>>>(Wq, Wk, Wv, Wtq, Wtk, Wtv);
  proj_kernel<<<dim3(128, 3), 512, 0, stream>>>(q, k, v, Wtq, Wtk, Wtv, bq, bk, bv, Qb, Kb, Vtb);
  if (nsplit == 4) {
    attn_kernel<16><<<dim3(32, 4, 4), 256, 0, stream>>>(Qb, Kb, Vtb, Po, ml);
    combine_kernel<4><<<2048, 256, 0, stream>>>(Po, ml, out);
  } else if (nsplit == 2) {
    attn_kernel<32><<<dim3(32, 2, 4), 256, 0, stream>>>(Qb, Kb, Vtb, Po, ml);
    combine_kernel<2><<<2048, 256, 0, stream>>>(Po, ml, out);
  } else {
    attn_kernel<64><<<dim3(32, 1, 4), 256, 0, stream>>>(Qb, Kb, Vtb, Po, ml);
    combine_kernel<1><<<2048, 256, 0, stream>>>(Po, ml, out);
  }
}

// Round 10
// 103.276 us; speedup vs baseline: 1.7011x; 1.0036x over previous
//
#include <hip/hip_runtime.h>
#include <hip/hip_bf16.h>
#include <cstdint>
#include <cmath>

// Shapes (hard-coded): B=4, S=4096, D=1024, DK=DV=128.
// ws layout: Qb[16384][128]bf16 @0 (4MB) | Kb @4MB | Vt[B][128][4096]bf16 @8MB
//            | Wtq bf16[128][1024] @12MB | Wtk | Wtv (ends 12.75MB)
//            | Po[nsplit][16384][128]f32 @13MB | ml[nsplit][16384][2]f32 after.

typedef __bf16 bf16x8 __attribute__((ext_vector_type(8)));
typedef float f32x4 __attribute__((ext_vector_type(4)));
typedef float f32x16 __attribute__((ext_vector_type(16)));

typedef const __attribute__((address_space(1))) unsigned int* gp_t;
typedef __attribute__((address_space(3))) unsigned int* lp_t;

__device__ __forceinline__ unsigned short f2bf(float f) {
  unsigned u = __float_as_uint(f);
  u += 0x7fffu + ((u >> 16) & 1u);   // RNE
  return (unsigned short)(u >> 16);
}

__device__ __forceinline__ bf16x8 ld_frag(const char* p) {
  uint4 u = *reinterpret_cast<const uint4*>(p);
  return __builtin_bit_cast(bf16x8, u);
}

__device__ __forceinline__ unsigned cvtpk_bf16(float lo, float hi) {
  unsigned r;
  asm("v_cvt_pk_bf16_f32 %0, %1, %2" : "=v"(r) : "v"(lo), "v"(hi));
  return r;
}

__device__ __forceinline__ void pl32swap(unsigned &a, unsigned &b) {
  asm("v_permlane32_swap_b32 %0, %1" : "+v"(a), "+v"(b));
}

__device__ __forceinline__ bf16x8 mk_frag(unsigned w0, unsigned w1, unsigned w2, unsigned w3) {
  uint4 u{w0, w1, w2, w3};
  return __builtin_bit_cast(bf16x8, u);
}

__device__ __forceinline__ bf16x8 cvt_frag(const float4& f0, const float4& f1) {
  return mk_frag(cvtpk_bf16(f0.x, f0.y), cvtpk_bf16(f0.z, f0.w),
                 cvtpk_bf16(f1.x, f1.y), cvtpk_bf16(f1.z, f1.w));
}

// Q is pre-scaled by (1/sqrt(128)) * log2(e) so softmax uses exp2 directly.
#define QSCALE_LOG2E 0.12751744f

// ---------------- W transpose: [1024][128] f32 -> [128][1024] bf16 ----------
__global__ __launch_bounds__(256) void prep_wt_kernel(
    const float* __restrict__ W0, const float* __restrict__ W1, const float* __restrict__ W2,
    unsigned short* __restrict__ T0, unsigned short* __restrict__ T1,
    unsigned short* __restrict__ T2) {
  const int mode = blockIdx.z;
  const float* W = (mode == 0) ? W0 : (mode == 1) ? W1 : W2;
  unsigned short* Wt = (mode == 0) ? T0 : (mode == 1) ? T1 : T2;
  __shared__ float tile[64][65];
  int kt = blockIdx.x, nt = blockIdx.y;   // (16, 2)
  int tid = threadIdx.x;
  int c = tid & 63;
  int r0 = (tid >> 6) * 16;
#pragma unroll
  for (int i = 0; i < 16; ++i) {
    int r = r0 + i;
    tile[r][c] = W[(size_t)(kt * 64 + r) * 128 + nt * 64 + c];
  }
  __syncthreads();
#pragma unroll
  for (int i = 0; i < 16; ++i) {
    int n = r0 + i;
    Wt[(size_t)(nt * 64 + n) * 1024 + kt * 64 + c] = f2bf(tile[c][n]);
  }
}

// ---------------- projections: X[16384][1024]f32 @ Wt -> bf16 outputs -------
// BM=64, 4 waves; wave owns 16 M-rows x all 128 N-cols. Deep pipeline:
//   A: global->reg, 3-set register ring, issued t+3 ahead (~1200cy slack).
//   W: global_load_lds w16 into 3-slot LDS ring, issued t+2 ahead,
//      inverse-swizzled source. Per-iter: issue W(t+2); vmcnt(16); barrier;
//      cvt A(t); issue A(t+3); 16 MFMA; barrier. Never drains in main loop.
__global__ __launch_bounds__(256, 3) void proj_kernel(
    const float* __restrict__ qx, const float* __restrict__ kx, const float* __restrict__ vx,
    const unsigned short* __restrict__ Wtq, const unsigned short* __restrict__ Wtk,
    const unsigned short* __restrict__ Wtv,
    const float* __restrict__ bq, const float* __restrict__ bk, const float* __restrict__ bv,
    unsigned short* __restrict__ Qb, unsigned short* __restrict__ Kb,
    unsigned short* __restrict__ Vtb) {
  const int mode = blockIdx.y;  // 0=Q 1=K 2=V
  const float* x = (mode == 0) ? qx : (mode == 1) ? kx : vx;
  const unsigned short* Wt = (mode == 0) ? Wtq : (mode == 1) ? Wtk : Wtv;
  const float* bias = (mode == 0) ? bq : (mode == 1) ? bk : bv;

  __shared__ __align__(16) char ldsW[49152];  // 3 x 16KB W tiles (128 x 64k bf16)

  const int tid = threadIdx.x;
  const int lane = tid & 63, wid = tid >> 6;   // 4 waves
  const int l15 = lane & 15, hi = lane >> 4;
  const long row0 = (long)blockIdx.x * 64;

  // A: lane reads row (row0 + wid*16 + l15), k = t*64 + kk*32 + hi*8
  const float* a_base = x + (row0 + wid * 16 + l15) * 1024 + hi * 8;

  // W staging: thread stages 4x16B. Linear LDS byte = i*4096 + tid*16 ->
  // row = i*32 + (tid>>3), col16 = tid&7; source col pre-swizzled (involution).
  const char* w_src = (const char*)Wt + (size_t)(tid >> 3) * 2048 +
                      (size_t)((tid & 7) ^ ((tid >> 3) & 7)) * 16;

  f32x4 acc[8];
#pragma unroll
  for (int i = 0; i < 8; ++i) acc[i] = f32x4{0.f, 0.f, 0.f, 0.f};

  float4 aA[4], aB[4], aC[4];  // 3-deep A register ring

#define PROJ_A_ISSUE(TS, SET)                                                         \
  {                                                                                   \
    const float* an_ = a_base + (TS) * 64;                                            \
    SET[0] = *reinterpret_cast<const float4*>(an_ + 0);                               \
    SET[1] = *reinterpret_cast<const float4*>(an_ + 4);                               \
    SET[2] = *reinterpret_cast<const float4*>(an_ + 32);                              \
    SET[3] = *reinterpret_cast<const float4*>(an_ + 36);                              \
  }

#define PROJ_W_ISSUE(TS)                                                              \
  {                                                                                   \
    char* lw_ = ldsW + ((TS) % 3) * 16384;                                            \
    _Pragma("unroll")                                                                 \
    for (int i = 0; i < 4; ++i)                                                       \
      __builtin_amdgcn_global_load_lds((gp_t)(w_src + (size_t)i * 65536 + (TS) * 128),\
                                       (lp_t)(lw_ + i * 4096 + wid * 1024), 16, 0, 0);\
  }

  // prologue (interleaved so vmcnt ordering works): A0,W0,A1,W1,A2
  PROJ_A_ISSUE(0, aA);
  PROJ_W_ISSUE(0);
  PROJ_A_ISSUE(1, aB);
  PROJ_W_ISSUE(1);
  PROJ_A_ISSUE(2, aC);

#define PROJ_ITER(T, SET, VM)                                                         \
  {                                                                                   \
    if ((T) + 2 <= 15) PROJ_W_ISSUE((T) + 2);                                         \
    asm volatile("s_waitcnt vmcnt(" #VM ")" ::: "memory");                            \
    __builtin_amdgcn_s_barrier();                                                     \
    __builtin_amdgcn_sched_barrier(0);                                                \
    bf16x8 af0 = cvt_frag(SET[0], SET[1]);                                            \
    bf16x8 af1 = cvt_frag(SET[2], SET[3]);                                            \
    if ((T) + 3 <= 15) PROJ_A_ISSUE((T) + 3, SET);                                    \
    char* lwc_ = ldsW + ((T) % 3) * 16384;                                            \
    __builtin_amdgcn_s_setprio(1);                                                    \
    _Pragma("unroll")                                                                 \
    for (int ni = 0; ni < 8; ++ni) {                                                  \
      int row = ni * 16 + l15;                                                        \
      int swz = (row & 7) << 4;                                                       \
      bf16x8 wf0 = ld_frag(lwc_ + ((row * 128 + hi * 16) ^ swz));                     \
      bf16x8 wf1 = ld_frag(lwc_ + ((row * 128 + 64 + hi * 16) ^ swz));                \
      acc[ni] = __builtin_amdgcn_mfma_f32_16x16x32_bf16(af0, wf0, acc[ni], 0, 0, 0);  \
      acc[ni] = __builtin_amdgcn_mfma_f32_16x16x32_bf16(af1, wf1, acc[ni], 0, 0, 0);  \
    }                                                                                 \
    __builtin_amdgcn_s_setprio(0);                                                    \
    __builtin_amdgcn_s_barrier();                                                     \
    __builtin_amdgcn_sched_barrier(0);                                                \
  }

  PROJ_ITER(0, aA, 16)  PROJ_ITER(1, aB, 16)  PROJ_ITER(2, aC, 16)
  PROJ_ITER(3, aA, 16)  PROJ_ITER(4, aB, 16)  PROJ_ITER(5, aC, 16)
  PROJ_ITER(6, aA, 16)  PROJ_ITER(7, aB, 16)  PROJ_ITER(8, aC, 16)
  PROJ_ITER(9, aA, 16)  PROJ_ITER(10, aB, 16) PROJ_ITER(11, aC, 16)
  PROJ_ITER(12, aA, 16) PROJ_ITER(13, aB, 16) PROJ_ITER(14, aC, 8)
  PROJ_ITER(15, aA, 0)

#undef PROJ_ITER
#undef PROJ_W_ISSUE
#undef PROJ_A_ISSUE

  // epilogue: +bias, (Q: * scale), store. C: col(n16)=l15, row = hi*4 + reg.
#pragma unroll
  for (int ni = 0; ni < 8; ++ni) {
    int n = ni * 16 + l15;
    float bv_ = bias[n];
    long m = row0 + wid * 16 + hi * 4;
    f32x4 a = acc[ni];
    if (mode == 2) {
      int bb = (int)(m >> 12);
      int s = (int)(m & 4095);
      ushort4 pk;
      pk.x = f2bf(a.x + bv_); pk.y = f2bf(a.y + bv_);
      pk.z = f2bf(a.z + bv_); pk.w = f2bf(a.w + bv_);
      *reinterpret_cast<ushort4*>(Vtb + ((size_t)(bb * 128 + n)) * 4096 + s) = pk;
    } else {
      const float sc = (mode == 0) ? QSCALE_LOG2E : 1.0f;
      unsigned short* outp = (mode == 0) ? Qb : Kb;
      outp[(m + 0) * 128 + n] = f2bf((a.x + bv_) * sc);
      outp[(m + 1) * 128 + n] = f2bf((a.y + bv_) * sc);
      outp[(m + 2) * 128 + n] = f2bf((a.z + bv_) * sc);
      outp[(m + 3) * 128 + n] = f2bf((a.w + bv_) * sc);
    }
  }
}

// ---------------- flash attention (32x32 swapped, dbuf K/V + counted vmcnt) -
template <int TPS>
__global__ __launch_bounds__(256, 2) void attn_kernel(
    const unsigned short* __restrict__ Qb, const unsigned short* __restrict__ Kb,
    const unsigned short* __restrict__ Vtb, float* __restrict__ Po,
    float* __restrict__ ml) {
  __shared__ __align__(16) char lds[65536];  // K: 2x16KB @0, V: 2x16KB @32768

  const int tid = threadIdx.x;
  const int lane = tid & 63, wid = tid >> 6;
  const int l31 = lane & 31, hi = lane >> 5;
  const int split = blockIdx.y;
  const int b = blockIdx.z;
  const int qbase = blockIdx.x * 128 + wid * 32;  // within batch
  const size_t growq = (size_t)b * 4096 + qbase + l31;

  const char* kg0 = (const char*)Kb + (size_t)(b * 4096) * 256;
  const char* vg0 = (const char*)Vtb + (size_t)b * 128 * 4096 * 2;
  const int k_row = tid >> 4;
  const int k_csw = (tid & 15) ^ (k_row & 7);
  const int v_dv = tid >> 3;
  const int v_csw = (tid & 7) ^ (v_dv & 7);

#define ATTN_STAGE(KV0, BUF)                                                          \
  {                                                                                   \
    char* kb_ = lds + (BUF) * 16384;                                                  \
    char* vb_ = lds + 32768 + (BUF) * 16384;                                          \
    const char* kgs_ = kg0 + (size_t)(KV0) * 256 + (size_t)k_row * 256 + k_csw * 16;  \
    const char* vgs_ = vg0 + (size_t)(KV0) * 2 + (size_t)v_dv * 8192 + v_csw * 16;    \
    _Pragma("unroll")                                                                 \
    for (int i = 0; i < 4; ++i)                                                       \
      __builtin_amdgcn_global_load_lds((gp_t)(kgs_ + (size_t)i * 4096),               \
                                       (lp_t)(kb_ + i * 4096 + wid * 1024), 16, 0, 0);\
    _Pragma("unroll")                                                                 \
    for (int i = 0; i < 4; ++i)                                                       \
      __builtin_amdgcn_global_load_lds((gp_t)(vgs_ + (size_t)i * 262144),             \
                                       (lp_t)(vb_ + i * 4096 + wid * 1024), 16, 0, 0);\
  }

  bf16x8 qf[8];
  {
    const unsigned short* qp = Qb + growq * 128 + hi * 8;
#pragma unroll
    for (int kt = 0; kt < 8; ++kt)
      qf[kt] = __builtin_bit_cast(bf16x8, *reinterpret_cast<const uint4*>(qp + kt * 16));
  }

  f32x16 oacc[4];
#pragma unroll
  for (int d = 0; d < 4; ++d)
#pragma unroll
    for (int j = 0; j < 16; ++j) oacc[d][j] = 0.f;
  float mrun = -INFINITY, lrun = 0.f;

  const int t0 = split * TPS, t1 = t0 + TPS;

  ATTN_STAGE(t0 * 64, 0);
  ATTN_STAGE((t0 + 1) * 64, 1);

#pragma unroll 1
  for (int t = t0; t < t1; ++t) {
    const int buf = (t - t0) & 1;
    if (t < t1 - 1) asm volatile("s_waitcnt vmcnt(8)" ::: "memory");
    else            asm volatile("s_waitcnt vmcnt(0)" ::: "memory");
    __builtin_amdgcn_s_barrier();
    __builtin_amdgcn_sched_barrier(0);
    char* ldsK = lds + buf * 16384;
    char* ldsV = lds + 32768 + buf * 16384;

    f32x16 sc0, sc1;
#pragma unroll
    for (int j = 0; j < 16; ++j) { sc0[j] = 0.f; sc1[j] = 0.f; }
    __builtin_amdgcn_s_setprio(1);
#pragma unroll
    for (int kvb = 0; kvb < 2; ++kvb) {
      int row = kvb * 32 + l31;
      int rowoff = row * 256, swz = (row & 7) << 4;
#pragma unroll
      for (int kt = 0; kt < 8; ++kt) {
        bf16x8 kf = ld_frag(ldsK + ((rowoff + kt * 32 + hi * 16) ^ swz));
        if (kvb == 0) sc0 = __builtin_amdgcn_mfma_f32_32x32x16_bf16(kf, qf[kt], sc0, 0, 0, 0);
        else          sc1 = __builtin_amdgcn_mfma_f32_32x32x16_bf16(kf, qf[kt], sc1, 0, 0, 0);
      }
    }
    __builtin_amdgcn_s_setprio(0);

    float tmx[16];
#pragma unroll
    for (int i = 0; i < 16; ++i) tmx[i] = fmaxf(sc0[i], sc1[i]);
#pragma unroll
    for (int s = 8; s > 0; s >>= 1)
#pragma unroll
      for (int i = 0; i < s; ++i) tmx[i] = fmaxf(tmx[i], tmx[i + s]);
    float mt = tmx[0];
    mt = fmaxf(mt, __shfl_xor(mt, 32));

    if (!__all(mt - mrun <= 8.0f)) {
      float mnew = fmaxf(mrun, mt);
      float scl = exp2f(mrun - mnew);
      mrun = mnew;
      lrun *= scl;
#pragma unroll
      for (int d = 0; d < 4; ++d)
#pragma unroll
        for (int j = 0; j < 16; ++j) oacc[d][j] *= scl;
    }

#pragma unroll
    for (int i = 0; i < 16; ++i) {
      sc0[i] = exp2f(sc0[i] - mrun);
      sc1[i] = exp2f(sc1[i] - mrun);
    }
    float ts[16];
#pragma unroll
    for (int i = 0; i < 16; ++i) ts[i] = sc0[i] + sc1[i];
#pragma unroll
    for (int s = 8; s > 0; s >>= 1)
#pragma unroll
      for (int i = 0; i < s; ++i) ts[i] += ts[i + s];
    float psum = ts[0];
    psum += __shfl_xor(psum, 32);
    lrun += psum;

    bf16x8 pa[4];
#pragma unroll
    for (int c = 0; c < 2; ++c) {
      const f32x16& p = c ? sc1 : sc0;
#pragma unroll
      for (int g = 0; g < 2; ++g) {
        const int base = g * 8;
        unsigned a0 = cvtpk_bf16(p[base + 0], p[base + 1]);
        unsigned b0 = cvtpk_bf16(p[base + 4], p[base + 5]);
        pl32swap(a0, b0);
        unsigned a1 = cvtpk_bf16(p[base + 2], p[base + 3]);
        unsigned b1 = cvtpk_bf16(p[base + 6], p[base + 7]);
        pl32swap(a1, b1);
        pa[c * 2 + g] = mk_frag(a0, a1, b0, b1);
      }
    }

    __builtin_amdgcn_s_setprio(1);
#pragma unroll
    for (int dvb = 0; dvb < 4; ++dvb) {
      int vrow = dvb * 32 + l31;
      int voff = vrow * 128, vswz = (vrow & 7) << 4;
#pragma unroll
      for (int tt = 0; tt < 4; ++tt) {
        bf16x8 vf = ld_frag(ldsV + ((voff + tt * 32 + hi * 16) ^ vswz));
        oacc[dvb] = __builtin_amdgcn_mfma_f32_32x32x16_bf16(vf, pa[tt], oacc[dvb], 0, 0, 0);
      }
    }
    __builtin_amdgcn_s_setprio(0);

    __builtin_amdgcn_s_barrier();
    __builtin_amdgcn_sched_barrier(0);
    if (t + 2 < t1) ATTN_STAGE((t + 2) * 64, buf);
  }

#undef ATTN_STAGE

  if (hi == 0) {
    float* mlp = ml + (size_t)split * 32768 + growq * 2;
    mlp[0] = mrun; mlp[1] = lrun;
  }

  float* po = Po + ((size_t)split << 21) + ((size_t)b * 4096 + qbase) * 128;
  char* tbase = lds + wid * 4096;
  for (int dvb = 0; dvb < 4; ++dvb) {
#pragma unroll
    for (int g = 0; g < 4; ++g) {
      float4 w4{oacc[dvb][g * 4 + 0], oacc[dvb][g * 4 + 1],
                oacc[dvb][g * 4 + 2], oacc[dvb][g * 4 + 3]};
      int off = (l31 * 128 + g * 32 + hi * 16) ^ ((l31 & 7) << 4);
      *reinterpret_cast<float4*>(tbase + off) = w4;
    }
    asm volatile("s_waitcnt lgkmcnt(0)" ::: "memory");
    __builtin_amdgcn_sched_barrier(0);
#pragma unroll
    for (int qq = 0; qq < 4; ++qq) {
      int q = qq * 8 + (lane >> 3);
      int off = (q * 128 + (lane & 7) * 16) ^ ((q & 7) << 4);
      float4 r4 = *reinterpret_cast<const float4*>(tbase + off);
      *reinterpret_cast<float4*>(po + (size_t)q * 128 + dvb * 32 + (lane & 7) * 4) = r4;
    }
    asm volatile("s_waitcnt lgkmcnt(0)" ::: "memory");
    __builtin_amdgcn_sched_barrier(0);
  }
}

// ---------------- combine partials ------------------------------------------
template <int NS>
__global__ __launch_bounds__(256) void combine_kernel(const float* __restrict__ Po,
                                                      const float* __restrict__ ml,
                                                      float* __restrict__ out) {
  int idx = blockIdx.x * 256 + threadIdx.x;
  int grow = idx >> 5;
  int c4 = (idx & 31) * 4;
  float m[NS], l[NS];
  float M = -INFINITY;
#pragma unroll
  for (int s = 0; s < NS; ++s) {
    m[s] = ml[(size_t)s * 32768 + grow * 2 + 0];
    l[s] = ml[(size_t)s * 32768 + grow * 2 + 1];
    M = fmaxf(M, m[s]);
  }
  float L = 0.f, w[NS];
#pragma unroll
  for (int s = 0; s < NS; ++s) {
    w[s] = exp2f(m[s] - M);
    L += l[s] * w[s];
  }
  float invL = 1.0f / L;
  float4 acc = {0.f, 0.f, 0.f, 0.f};
#pragma unroll
  for (int s = 0; s < NS; ++s) {
    float4 p = *reinterpret_cast<const float4*>(Po + ((size_t)s << 21) + (size_t)grow * 128 + c4);
    acc.x += p.x * w[s]; acc.y += p.y * w[s];
    acc.z += p.z * w[s]; acc.w += p.w * w[s];
  }
  acc.x *= invL; acc.y *= invL; acc.z *= invL; acc.w *= invL;
  *reinterpret_cast<float4*>(out + (size_t)grow * 128 + c4) = acc;
}

extern "C" void kernel_launch(void* const* d_in, const int* in_sizes, int n_in,
                              void* d_out, int out_size, void* d_ws, size_t ws_size,
                              hipStream_t stream) {
  const float* q  = (const float*)d_in[0];
  const float* k  = (const float*)d_in[1];
  const float* v  = (const float*)d_in[2];
  const float* Wq = (const float*)d_in[3];
  const float* bq = (const float*)d_in[4];
  const float* Wk = (const float*)d_in[5];
  const float* bk = (const float*)d_in[6];
  const float* Wv = (const float*)d_in[7];
  const float* bv = (const float*)d_in[8];
  float* out = (float*)d_out;

  char* ws = (char*)d_ws;
  unsigned short* Qb  = (unsigned short*)(ws);
  unsigned short* Kb  = (unsigned short*)(ws + (4u << 20));
  unsigned short* Vtb = (unsigned short*)(ws + (8u << 20));
  unsigned short* Wtq = (unsigned short*)(ws + (12u << 20));
  unsigned short* Wtk = (unsigned short*)(ws + (12u << 20) + (256u << 10));
  unsigned short* Wtv = (unsigned short*)(ws + (12u << 20) + (512u << 10));

  const size_t base = (size_t)13 << 20;
  const size_t per = ((size_t)8 << 20) + ((size_t)128 << 10);
  int nsplit = 1;
  if (ws_size >= base + 4 * per) nsplit = 4;
  else if (ws_size >= base + 2 * per) nsplit = 2;
  float* Po = (float*)(ws + base);
  float* ml = (float*)(ws + base + (size_t)nsplit * ((size_t)8 << 20));

  prep_wt_kernel<<<dim3(16, 2, 3), 256, 0, stream>>>(Wq, Wk, Wv, Wtq, Wtk, Wtv);
  proj_kernel<<<dim3(256, 3), 256, 0, stream>>>(q, k, v, Wtq, Wtk, Wtv, bq, bk, bv, Qb, Kb, Vtb);
  if (nsplit == 4) {
    attn_kernel<16><<<dim3(32, 4, 4), 256, 0, stream>>>(Qb, Kb, Vtb, Po, ml);
    combine_kernel<4><<<2048, 256, 0, stream>>>(Po, ml, out);
  } else if (nsplit == 2) {
    attn_kernel<32><<<dim3(32, 2, 4), 256, 0, stream>>>(Qb, Kb, Vtb, Po, ml);
    combine_kernel<2><<<2048, 256, 0, stream>>>(Po, ml, out);
  } else {
    attn_kernel<64><<<dim3(32, 1, 4), 256, 0, stream>>>(Qb, Kb, Vtb, Po, ml);
    combine_kernel<1><<<2048, 256, 0, stream>>>(Po, ml, out);
  }
}